// Round 1
// baseline (8611.541 us; speedup 1.0000x reference)
//
#include <hip/hip_runtime.h>
#include <hip/hip_bf16.h>

typedef __bf16 bf16x8 __attribute__((ext_vector_type(8)));
typedef float  f32x4  __attribute__((ext_vector_type(4)));
using bf16 = __hip_bfloat16;

constexpr int Bv = 64, Tv = 128, Dv = 1024, Hv = 8, HDv = 128;
constexpr int NC = 1000, NS = 5, NM = 10;
constexpr int NT = Bv * Tv;           // 8192 tokens

static __device__ __forceinline__ float sigmoidf_(float x) {
  return 1.f / (1.f + __expf(-x));
}

// ---------------- generic bf16 MFMA GEMM: C[M,N] = A[M,K] @ W[N,K]^T + bias ----
// block = 256 threads (4 waves), tile 64x64, wave w owns rows w*16..w*16+15
__global__ __launch_bounds__(256) void gemm_bf16(
    const bf16* __restrict__ A, const bf16* __restrict__ W,
    const float* __restrict__ bias, bf16* __restrict__ C,
    int M, int N, int K)
{
  int wave = threadIdx.x >> 6;
  int lane = threadIdx.x & 63;
  int l15 = lane & 15, lhi = lane >> 4;
  int row0 = blockIdx.x * 64 + wave * 16;
  int col0 = blockIdx.y * 64;
  f32x4 acc[4];
#pragma unroll
  for (int i = 0; i < 4; ++i) acc[i] = f32x4{0.f, 0.f, 0.f, 0.f};
  const bf16* arow = A + (size_t)(row0 + l15) * K;
  for (int k0 = 0; k0 < K; k0 += 32) {
    int ko = k0 + lhi * 8;
    bf16x8 a = *reinterpret_cast<const bf16x8*>(arow + ko);
#pragma unroll
    for (int nt = 0; nt < 4; ++nt) {
      bf16x8 b = *reinterpret_cast<const bf16x8*>(
          W + (size_t)(col0 + nt * 16 + l15) * K + ko);
      acc[nt] = __builtin_amdgcn_mfma_f32_16x16x32_bf16(a, b, acc[nt], 0, 0, 0);
    }
  }
#pragma unroll
  for (int nt = 0; nt < 4; ++nt) {
    int col = col0 + nt * 16 + l15;
    float bv = bias ? bias[col] : 0.f;
#pragma unroll
    for (int r = 0; r < 4; ++r) {
      int rowi = row0 + lhi * 4 + r;
      C[(size_t)rowi * N + col] = __float2bfloat16(acc[nt][r] + bv);
    }
  }
}

// ---------------- f32 -> bf16 convert ----------------
__global__ void f2b_kernel(const float* __restrict__ s, bf16* __restrict__ d, int n4)
{
  int i = blockIdx.x * 256 + threadIdx.x;
  if (i < n4) {
    float4 v = ((const float4*)s)[i];
    bf16* o = d + (size_t)i * 4;
    o[0] = __float2bfloat16(v.x); o[1] = __float2bfloat16(v.y);
    o[2] = __float2bfloat16(v.z); o[3] = __float2bfloat16(v.w);
  }
}

__global__ void add2_kernel(const float* __restrict__ a, const float* __restrict__ b,
                            float* __restrict__ o, int n)
{
  int i = blockIdx.x * 256 + threadIdx.x;
  if (i < n) o[i] = a[i] + b[i];
}

// ---------------- stage/pos encoder: xpe16 = bf16(x + pos_emb) -----------------
__global__ __launch_bounds__(128) void encoder_kernel(
    const float* __restrict__ x, const int* __restrict__ stage,
    const float* __restrict__ w1, const float* __restrict__ b1,
    const float* __restrict__ g1, const float* __restrict__ bb1,
    const float* __restrict__ w2, const float* __restrict__ b2,
    const float* __restrict__ g2, const float* __restrict__ bb2,
    bf16* __restrict__ xpe)
{
  int tok = blockIdx.x;
  int t = tok & (Tv - 1);
  int tid = threadIdx.x;
  __shared__ float hb[64];
  __shared__ float rs[4];
  float stg = (float)stage[tok];
  if (tid < 64) {
    float v = w1[tid * 2] * (float)t + w1[tid * 2 + 1] * stg + b1[tid];
    float s = v, s2 = v * v;
    for (int off = 32; off; off >>= 1) { s += __shfl_down(s, off); s2 += __shfl_down(s2, off); }
    s = __shfl(s, 0); s2 = __shfl(s2, 0);
    float mu = s / 64.f, var = s2 / 64.f - mu * mu;
    float h = (v - mu) * rsqrtf(var + 1e-5f) * g1[tid] + bb1[tid];
    hb[tid] = fmaxf(h, 0.f);
  }
  __syncthreads();
  float outv[8];
  float s = 0.f, s2 = 0.f;
  int d0 = tid * 8;
#pragma unroll
  for (int o = 0; o < 8; ++o) {
    int d = d0 + o;
    float acc = b2[d];
    const float4* wr = (const float4*)(w2 + (size_t)d * 64);
#pragma unroll
    for (int k4 = 0; k4 < 16; ++k4) {
      float4 w = wr[k4];
      acc += w.x * hb[k4 * 4] + w.y * hb[k4 * 4 + 1] + w.z * hb[k4 * 4 + 2] + w.w * hb[k4 * 4 + 3];
    }
    outv[o] = acc; s += acc; s2 += acc * acc;
  }
  for (int off = 32; off; off >>= 1) { s += __shfl_down(s, off); s2 += __shfl_down(s2, off); }
  int wid = tid >> 6;
  if ((tid & 63) == 0) { rs[wid] = s; rs[2 + wid] = s2; }
  __syncthreads();
  s = rs[0] + rs[1]; s2 = rs[2] + rs[3];
  float mu = s / 1024.f, var = s2 / 1024.f - mu * mu;
  float rstd = rsqrtf(var + 1e-5f);
  const float* xr = x + (size_t)tok * Dv;
  bf16* op = xpe + (size_t)tok * Dv + d0;
#pragma unroll
  for (int o = 0; o < 8; ++o) {
    int d = d0 + o;
    float e = (outv[o] - mu) * rstd * g2[d] + bb2[d];
    op[o] = __float2bfloat16(xr[d] + e);
  }
}

// ---------------- attention: per (b,h) flash-style, scalar fp32 ----------------
__global__ __launch_bounds__(256) void attn_kernel(const bf16* __restrict__ qkv,
                                                   bf16* __restrict__ o)
{
  __shared__ bf16 kl[128][128];
  __shared__ bf16 vl[128][128];
  int bh = blockIdx.x;
  int b = bh >> 3, h = bh & 7;
  int tid = threadIdx.x;
  int row = tid >> 1, hf = tid & 1;
  {
    const bf16* ks = qkv + (size_t)(b * Tv + row) * 3072 + Dv + h * HDv + hf * 64;
    const bf16* vs = ks + Dv;
    uint4* dk = (uint4*)&kl[row][hf * 64];
    uint4* dv = (uint4*)&vl[row][hf * 64];
    const uint4* sk = (const uint4*)ks;
    const uint4* sv = (const uint4*)vs;
#pragma unroll
    for (int i = 0; i < 8; ++i) { dk[i] = sk[i]; dv[i] = sv[i]; }
  }
  float qf[64];
  {
    const bf16* qs = qkv + (size_t)(b * Tv + row) * 3072 + h * HDv + hf * 64;
#pragma unroll
    for (int d2 = 0; d2 < 32; ++d2) {
      float2 f = __bfloat1622float2(*(const __hip_bfloat162*)(qs + 2 * d2));
      qf[2 * d2] = f.x; qf[2 * d2 + 1] = f.y;
    }
  }
  __syncthreads();
  float oacc[64];
#pragma unroll
  for (int d = 0; d < 64; ++d) oacc[d] = 0.f;
  float m = -1e30f, l = 0.f;
  const float scale = 0.088388347648318447f;  // 1/sqrt(128)
  for (int j = 0; j < 128; ++j) {
    float part = 0.f;
#pragma unroll
    for (int d2 = 0; d2 < 32; ++d2) {
      float2 kv2 = __bfloat1622float2(*(const __hip_bfloat162*)&kl[j][hf * 64 + 2 * d2]);
      part += qf[2 * d2] * kv2.x + qf[2 * d2 + 1] * kv2.y;
    }
    float sfull = (part + __shfl_xor(part, 1)) * scale;
    float mn = fmaxf(m, sfull);
    float al = __expf(m - mn);
    float p = __expf(sfull - mn);
    l = l * al + p;
#pragma unroll
    for (int d2 = 0; d2 < 32; ++d2) {
      float2 vv = __bfloat1622float2(*(const __hip_bfloat162*)&vl[j][hf * 64 + 2 * d2]);
      oacc[2 * d2]     = oacc[2 * d2] * al + p * vv.x;
      oacc[2 * d2 + 1] = oacc[2 * d2 + 1] * al + p * vv.y;
    }
    m = mn;
  }
  float rl = 1.f / l;
  bf16* od = o + (size_t)(b * Tv + row) * Dv + h * HDv + hf * 64;
#pragma unroll
  for (int d = 0; d < 64; ++d) od[d] = __float2bfloat16(oacc[d] * rl);
}

// ---------------- residual + LN -> raw (f32 to d_out) + raw16 -----------------
__global__ __launch_bounds__(256) void residual_ln_kernel(
    const bf16* __restrict__ xpe, const bf16* __restrict__ ao,
    const float* __restrict__ gam, const float* __restrict__ bet,
    float* __restrict__ rawf, bf16* __restrict__ raw16)
{
  int tok = blockIdx.x, tid = threadIdx.x;
  float v[4]; float s = 0.f, s2 = 0.f;
  __shared__ float rs[8];
#pragma unroll
  for (int q = 0; q < 4; ++q) {
    int d = tid + q * 256;
    size_t idx = (size_t)tok * Dv + d;
    float a = __bfloat162float(xpe[idx]) + __bfloat162float(ao[idx]);
    v[q] = a; s += a; s2 += a * a;
  }
  for (int off = 32; off; off >>= 1) { s += __shfl_down(s, off); s2 += __shfl_down(s2, off); }
  int wid = tid >> 6;
  if ((tid & 63) == 0) { rs[wid] = s; rs[4 + wid] = s2; }
  __syncthreads();
  s = rs[0] + rs[1] + rs[2] + rs[3];
  s2 = rs[4] + rs[5] + rs[6] + rs[7];
  float mu = s / 1024.f, var = s2 / 1024.f - mu * mu;
  float rstd = rsqrtf(var + 1e-5f);
#pragma unroll
  for (int q = 0; q < 4; ++q) {
    int d = tid + q * 256;
    size_t idx = (size_t)tok * Dv + d;
    float rv = (v[q] - mu) * rstd * gam[d] + bet[d];
    rawf[idx] = rv;
    raw16[idx] = __float2bfloat16(rv);
  }
}

// ---------------- LSTM step: gates = xg[t] + h @ Whh^T ; update c,h -----------
// 64 blocks x 256 threads. block owns units u0..u0+15 (all 4 gates). wave = gate.
__global__ __launch_bounds__(256) void lstm_step_kernel(
    const bf16* __restrict__ h_in, const bf16* __restrict__ Whh,
    const bf16* __restrict__ xg_t,           // + t*4096; row stride T*4096 per batch
    float* __restrict__ c, bf16* __restrict__ h_out,
    bf16* __restrict__ yout,                  // layer0: y0 + t*1024 (stride T*1024), else null
    float* __restrict__ pooled)               // layer1 last step only, else null
{
  int u0 = blockIdx.x * 16;
  int g = threadIdx.x >> 6;
  int lane = threadIdx.x & 63;
  int l15 = lane & 15, lhi = lane >> 4;
  f32x4 a0 = f32x4{0.f,0.f,0.f,0.f}, a1 = a0, a2 = a0, a3 = a0;
  const bf16* wrow = Whh + (size_t)(g * Dv + u0 + l15) * Dv;
  const bf16* h0 = h_in + (size_t)l15 * Dv;
  for (int k0 = 0; k0 < Dv; k0 += 32) {
    int ko = k0 + lhi * 8;
    bf16x8 bf = *reinterpret_cast<const bf16x8*>(wrow + ko);
    bf16x8 f0 = *reinterpret_cast<const bf16x8*>(h0 + ko);
    bf16x8 f1 = *reinterpret_cast<const bf16x8*>(h0 + 16 * Dv + ko);
    bf16x8 f2 = *reinterpret_cast<const bf16x8*>(h0 + 32 * Dv + ko);
    bf16x8 f3 = *reinterpret_cast<const bf16x8*>(h0 + 48 * Dv + ko);
    a0 = __builtin_amdgcn_mfma_f32_16x16x32_bf16(f0, bf, a0, 0, 0, 0);
    a1 = __builtin_amdgcn_mfma_f32_16x16x32_bf16(f1, bf, a1, 0, 0, 0);
    a2 = __builtin_amdgcn_mfma_f32_16x16x32_bf16(f2, bf, a2, 0, 0, 0);
    a3 = __builtin_amdgcn_mfma_f32_16x16x32_bf16(f3, bf, a3, 0, 0, 0);
  }
  __shared__ float gl[4][64][16];
#pragma unroll
  for (int m = 0; m < 4; ++m) {
    f32x4 av = (m == 0) ? a0 : (m == 1) ? a1 : (m == 2) ? a2 : a3;
#pragma unroll
    for (int r = 0; r < 4; ++r) {
      int bb = m * 16 + lhi * 4 + r;
      float xv = __bfloat162float(xg_t[(size_t)bb * (Tv * 4 * Dv) + g * Dv + u0 + l15]);
      gl[g][bb][l15] = av[r] + xv;
    }
  }
  __syncthreads();
  int base = threadIdx.x * 4;
#pragma unroll
  for (int q = 0; q < 4; ++q) {
    int p = base + q;
    int bb = p >> 4, uu = p & 15;
    float gi = gl[0][bb][uu], gf = gl[1][bb][uu], gc = gl[2][bb][uu], go = gl[3][bb][uu];
    int ci = bb * Dv + u0 + uu;
    float cn = sigmoidf_(gf) * c[ci] + sigmoidf_(gi) * tanhf(gc);
    float hn = sigmoidf_(go) * tanhf(cn);
    c[ci] = cn;
    h_out[ci] = __float2bfloat16(hn);
    if (yout) yout[(size_t)bb * (Tv * Dv) + u0 + uu] = __float2bfloat16(hn);
    if (pooled) pooled[ci] = hn;
  }
}

// ---------------- raw_mean over T ----------------
__global__ void rawmean_kernel(const float* __restrict__ raw, float* __restrict__ out)
{
  int i = blockIdx.x * 256 + threadIdx.x;   // 65536
  int b = i >> 10, d = i & 1023;
  const float* r = raw + (size_t)b * Tv * Dv + d;
  float s = 0.f;
  for (int t = 0; t < Tv; ++t) s += r[(size_t)t * Dv];
  out[i] = s * (1.f / Tv);
}

// ---------------- gated fusion ----------------
__global__ __launch_bounds__(256) void gate1_kernel(
    const float* __restrict__ pooled, const float* __restrict__ rawmean,
    const float* __restrict__ w1, const float* __restrict__ b1, float* __restrict__ out)
{
  int b = blockIdx.x;
  __shared__ float cat[2048];
  for (int k = threadIdx.x; k < 1024; k += 256) {
    cat[k] = pooled[b * 1024 + k];
    cat[1024 + k] = rawmean[b * 1024 + k];
  }
  __syncthreads();
  for (int jj = 0; jj < 4; ++jj) {
    int j = threadIdx.x + jj * 256;
    float acc = b1[j];
    const float4* wr = (const float4*)(w1 + (size_t)j * 2048);
    for (int k4 = 0; k4 < 512; ++k4) {
      float4 w = wr[k4];
      acc += w.x * cat[k4 * 4] + w.y * cat[k4 * 4 + 1] + w.z * cat[k4 * 4 + 2] + w.w * cat[k4 * 4 + 3];
    }
    out[b * 1024 + j] = fmaxf(acc, 0.f);
  }
}

__global__ __launch_bounds__(256) void gate2_kernel(
    const float* __restrict__ gt1, const float* __restrict__ pooled,
    const float* __restrict__ rawmean,
    const float* __restrict__ w2, const float* __restrict__ b2, float* __restrict__ fused)
{
  int b = blockIdx.x;
  __shared__ float cl[1024];
  for (int k = threadIdx.x; k < 1024; k += 256) cl[k] = gt1[b * 1024 + k];
  __syncthreads();
  for (int jj = 0; jj < 4; ++jj) {
    int j = threadIdx.x + jj * 256;
    float acc = b2[j];
    const float4* wr = (const float4*)(w2 + (size_t)j * 1024);
    for (int k4 = 0; k4 < 256; ++k4) {
      float4 w = wr[k4];
      acc += w.x * cl[k4 * 4] + w.y * cl[k4 * 4 + 1] + w.z * cl[k4 * 4 + 2] + w.w * cl[k4 * 4 + 3];
    }
    float gv = sigmoidf_(acc);
    int idx = b * 1024 + j;
    fused[idx] = gv * pooled[idx] + (1.f - gv) * rawmean[idx];
  }
}

// ---------------- stage head ----------------
__global__ __launch_bounds__(128) void head_kernel(
    const float* __restrict__ fused,
    const float* __restrict__ w1, const float* __restrict__ b1,
    const float* __restrict__ gam, const float* __restrict__ bet,
    const float* __restrict__ w2, const float* __restrict__ b2,
    float* __restrict__ logits)
{
  int b = blockIdx.x;
  __shared__ float fl[1024];
  __shared__ float h1[512];
  __shared__ float rs[4];
  for (int k = threadIdx.x; k < 1024; k += 128) fl[k] = fused[b * 1024 + k];
  __syncthreads();
  float vals[4]; float s = 0.f, s2 = 0.f;
  for (int jj = 0; jj < 4; ++jj) {
    int j = threadIdx.x + jj * 128;
    float acc = b1[j];
    const float4* wr = (const float4*)(w1 + (size_t)j * 1024);
    for (int k4 = 0; k4 < 256; ++k4) {
      float4 w = wr[k4];
      acc += w.x * fl[k4 * 4] + w.y * fl[k4 * 4 + 1] + w.z * fl[k4 * 4 + 2] + w.w * fl[k4 * 4 + 3];
    }
    vals[jj] = acc; s += acc; s2 += acc * acc;
  }
  for (int off = 32; off; off >>= 1) { s += __shfl_down(s, off); s2 += __shfl_down(s2, off); }
  int wid = threadIdx.x >> 6;
  if ((threadIdx.x & 63) == 0) { rs[wid] = s; rs[2 + wid] = s2; }
  __syncthreads();
  s = rs[0] + rs[1]; s2 = rs[2] + rs[3];
  float mu = s / 512.f, var = s2 / 512.f - mu * mu;
  float rstd = rsqrtf(var + 1e-5f);
  for (int jj = 0; jj < 4; ++jj) {
    int j = threadIdx.x + jj * 128;
    h1[j] = fmaxf((vals[jj] - mu) * rstd * gam[j] + bet[j], 0.f);
  }
  __syncthreads();
  if (threadIdx.x < 5) {
    float acc = b2[threadIdx.x];
    for (int k = 0; k < 512; ++k) acc += h1[k] * w2[threadIdx.x * 512 + k];
    logits[b * 5 + threadIdx.x] = acc;
  }
}

// ---------------- memory bank update ----------------
__global__ void scatter_last_kernel(const int* __restrict__ cls,
                                    const int* __restrict__ stage, int* __restrict__ last)
{
  int i = blockIdx.x * 256 + threadIdx.x;
  if (i < NT) {
    int b = i >> 7;
    int p = cls[b] * NS + stage[i];
    atomicMax(&last[p], i);
  }
}

__global__ __launch_bounds__(256) void mem_update_kernel(
    const float* __restrict__ mem_in, const float* __restrict__ raw,
    const int* __restrict__ cnt_in, const int* __restrict__ last,
    float* __restrict__ mem_out, float* __restrict__ cnt_out)
{
  int p = blockIdx.x;
  int cnt = cnt_in[p];
  int li = last[p];
  bool present = li >= 0;
  bool full = cnt >= NM;
  int wp = full ? NM - 1 : cnt;
  const float* newf = raw + (size_t)(li < 0 ? 0 : li) * Dv;
  const float* src = mem_in + (size_t)p * NM * Dv;
  float* dst = mem_out + (size_t)p * NM * Dv;
  for (int idx = threadIdx.x; idx < NM * Dv / 4; idx += 256) {
    int m = idx >> 8;          // 256 float4 per row
    int dq = idx & 255;
    float4 v;
    if (present && full) {
      v = (m < NM - 1) ? *(const float4*)(src + (size_t)(m + 1) * Dv + dq * 4)
                       : *(const float4*)(newf + dq * 4);
    } else if (present) {
      v = (m == wp) ? *(const float4*)(newf + dq * 4)
                    : *(const float4*)(src + (size_t)m * Dv + dq * 4);
    } else {
      v = *(const float4*)(src + (size_t)m * Dv + dq * 4);
    }
    *(float4*)(dst + (size_t)m * Dv + dq * 4) = v;
  }
  if (threadIdx.x == 0)
    cnt_out[p] = (float)(cnt + ((present && !full) ? 1 : 0));
}

// =======================================================================
extern "C" void kernel_launch(void* const* d_in, const int* in_sizes, int n_in,
                              void* d_out, int out_size, void* d_ws, size_t ws_size,
                              hipStream_t stream)
{
  (void)in_sizes; (void)n_in; (void)out_size; (void)ws_size;
  const float* x       = (const float*)d_in[0];
  const int* stage     = (const int*)d_in[1];
  const int* cls       = (const int*)d_in[2];
  const float* enc_w1  = (const float*)d_in[3];
  const float* enc_b1  = (const float*)d_in[4];
  const float* enc_g1  = (const float*)d_in[5];
  const float* enc_bb1 = (const float*)d_in[6];
  const float* enc_w2  = (const float*)d_in[7];
  const float* enc_b2  = (const float*)d_in[8];
  const float* enc_g2  = (const float*)d_in[9];
  const float* enc_bb2 = (const float*)d_in[10];
  const float* qkv_w   = (const float*)d_in[11];
  const float* qkv_b   = (const float*)d_in[12];
  const float* out_w   = (const float*)d_in[13];
  const float* out_b   = (const float*)d_in[14];
  const float* norm_g  = (const float*)d_in[15];
  const float* norm_b  = (const float*)d_in[16];
  const float* Wih0    = (const float*)d_in[17];
  const float* Whh0    = (const float*)d_in[18];
  const float* bih0    = (const float*)d_in[19];
  const float* bhh0    = (const float*)d_in[20];
  const float* Wih1    = (const float*)d_in[21];
  const float* Whh1    = (const float*)d_in[22];
  const float* bih1    = (const float*)d_in[23];
  const float* bhh1    = (const float*)d_in[24];
  const float* head_w1 = (const float*)d_in[25];
  const float* head_b1 = (const float*)d_in[26];
  const float* head_g  = (const float*)d_in[27];
  const float* head_bb = (const float*)d_in[28];
  const float* head_w2 = (const float*)d_in[29];
  const float* head_b2 = (const float*)d_in[30];
  const float* gate_w1 = (const float*)d_in[31];
  const float* gate_b1 = (const float*)d_in[32];
  const float* gate_w2 = (const float*)d_in[33];
  const float* gate_b2 = (const float*)d_in[34];
  const float* mem_in  = (const float*)d_in[35];
  const int* cnt_in    = (const int*)d_in[36];

  float* out = (float*)d_out;
  float* out_fused  = out;                      // 65536
  float* out_raw    = out + 65536;              // 8388608
  float* out_logits = out + 8454144;            // 320
  float* out_mem    = out + 8454464;            // 51200000
  float* out_cnt    = out + 59654464;           // 5000

  // ---- workspace layout (small stuff + bf16 weights), ~43 MB ----
  char* wsb = (char*)d_ws;
  auto alloc = [&](size_t bytes) { char* p = wsb; wsb += (bytes + 255) & ~(size_t)255; return p; };
  bf16* wq16   = (bf16*)alloc((size_t)3072 * 1024 * 2);
  bf16* wo16   = (bf16*)alloc((size_t)1024 * 1024 * 2);
  bf16* wih0b  = (bf16*)alloc((size_t)4096 * 1024 * 2);
  bf16* whh0b  = (bf16*)alloc((size_t)4096 * 1024 * 2);
  bf16* wih1b  = (bf16*)alloc((size_t)4096 * 1024 * 2);
  bf16* whh1b  = (bf16*)alloc((size_t)4096 * 1024 * 2);
  float* bsum0 = (float*)alloc(4096 * 4);
  float* bsum1 = (float*)alloc(4096 * 4);
  bf16* hbuf0  = (bf16*)alloc(65536 * 2);
  bf16* hbuf1  = (bf16*)alloc(65536 * 2);
  float* cbuf  = (float*)alloc(65536 * 4);
  float* pooled  = (float*)alloc(65536 * 4);
  float* rawmean = (float*)alloc(65536 * 4);
  float* gt1     = (float*)alloc(65536 * 4);
  int* last      = (int*)alloc(5000 * 4);

  // ---- large activation scratch inside the new_mem output slot (204.8 MB),
  //      all uses finish before mem_update overwrites it ----
  char* orb = (char*)out_mem;
  bf16* qkv16 = (bf16*)(orb + 0);            // 50,331,648 B
  bf16* y016  = (bf16*)(orb + 50331648);     // 16,777,216 B
  bf16* xg16  = (bf16*)(orb + 67108864);     // 67,108,864 B
  bf16* xpe16 = (bf16*)(orb + 134217728);    // 16,777,216 B
  bf16* o16   = (bf16*)(orb + 150994944);    // 16,777,216 B
  bf16* ao16  = (bf16*)(orb + 167772160);    // 16,777,216 B
  bf16* raw16 = (bf16*)(orb + 184549376);    // 16,777,216 B (ends 201,326,592)

  // 1) weight conversions + bias sums
  f2b_kernel<<<3072, 256, 0, stream>>>(qkv_w, wq16, 786432);
  f2b_kernel<<<1024, 256, 0, stream>>>(out_w, wo16, 262144);
  f2b_kernel<<<4096, 256, 0, stream>>>(Wih0, wih0b, 1048576);
  f2b_kernel<<<4096, 256, 0, stream>>>(Whh0, whh0b, 1048576);
  f2b_kernel<<<4096, 256, 0, stream>>>(Wih1, wih1b, 1048576);
  f2b_kernel<<<4096, 256, 0, stream>>>(Whh1, whh1b, 1048576);
  add2_kernel<<<16, 256, 0, stream>>>(bih0, bhh0, bsum0, 4096);
  add2_kernel<<<16, 256, 0, stream>>>(bih1, bhh1, bsum1, 4096);

  // 2) encoder -> xpe16
  encoder_kernel<<<NT, 128, 0, stream>>>(x, stage, enc_w1, enc_b1, enc_g1, enc_bb1,
                                         enc_w2, enc_b2, enc_g2, enc_bb2, xpe16);

  // 3) qkv = xpe @ qkv_w^T + b
  gemm_bf16<<<dim3(NT / 64, 3072 / 64), 256, 0, stream>>>(xpe16, wq16, qkv_b, qkv16, NT, 3072, Dv);

  // 4) attention -> o16
  attn_kernel<<<Bv * Hv, 256, 0, stream>>>(qkv16, o16);

  // 5) out projection -> ao16
  gemm_bf16<<<dim3(NT / 64, 1024 / 64), 256, 0, stream>>>(o16, wo16, out_b, ao16, NT, Dv, Dv);

  // 6) residual + LN -> raw (d_out) + raw16
  residual_ln_kernel<<<NT, 256, 0, stream>>>(xpe16, ao16, norm_g, norm_b, out_raw, raw16);

  // 7) LSTM layer 0
  gemm_bf16<<<dim3(NT / 64, 4096 / 64), 256, 0, stream>>>(raw16, wih0b, bsum0, xg16, NT, 4096, Dv);
  hipMemsetAsync(hbuf0, 0, 65536 * 2, stream);
  hipMemsetAsync(cbuf, 0, 65536 * 4, stream);
  for (int t = 0; t < Tv; ++t) {
    const bf16* hi = (t & 1) ? hbuf1 : hbuf0;
    bf16* ho = (t & 1) ? hbuf0 : hbuf1;
    lstm_step_kernel<<<64, 256, 0, stream>>>(hi, whh0b, xg16 + (size_t)t * 4096,
                                             cbuf, ho, y016 + (size_t)t * Dv, nullptr);
  }

  // 8) LSTM layer 1
  gemm_bf16<<<dim3(NT / 64, 4096 / 64), 256, 0, stream>>>(y016, wih1b, bsum1, xg16, NT, 4096, Dv);
  hipMemsetAsync(hbuf0, 0, 65536 * 2, stream);
  hipMemsetAsync(cbuf, 0, 65536 * 4, stream);
  for (int t = 0; t < Tv; ++t) {
    const bf16* hi = (t & 1) ? hbuf1 : hbuf0;
    bf16* ho = (t & 1) ? hbuf0 : hbuf1;
    lstm_step_kernel<<<64, 256, 0, stream>>>(hi, whh1b, xg16 + (size_t)t * 4096,
                                             cbuf, ho, nullptr, (t == Tv - 1) ? pooled : nullptr);
  }

  // 9) raw_mean, gated fusion, head
  rawmean_kernel<<<256, 256, 0, stream>>>(out_raw, rawmean);
  gate1_kernel<<<Bv, 256, 0, stream>>>(pooled, rawmean, gate_w1, gate_b1, gt1);
  gate2_kernel<<<Bv, 256, 0, stream>>>(gt1, pooled, rawmean, gate_w2, gate_b2, out_fused);
  head_kernel<<<Bv, 128, 0, stream>>>(out_fused, head_w1, head_b1, head_g, head_bb,
                                      head_w2, head_b2, out_logits);

  // 10) memory bank update (overwrites the scratch region last)
  hipMemsetAsync(last, 0xFF, 5000 * 4, stream);
  scatter_last_kernel<<<32, 256, 0, stream>>>(cls, stage, last);
  mem_update_kernel<<<NC * NS, 256, 0, stream>>>(mem_in, out_raw, cnt_in, last, out_mem, out_cnt);
}

// Round 2
// 6495.432 us; speedup vs baseline: 1.3258x; 1.3258x over previous
//
#include <hip/hip_runtime.h>
#include <hip/hip_bf16.h>

typedef __bf16 bf16x8 __attribute__((ext_vector_type(8)));
typedef float  f32x4  __attribute__((ext_vector_type(4)));
using bf16 = __hip_bfloat16;

constexpr int Bv = 64, Tv = 128, Dv = 1024, Hv = 8, HDv = 128;
constexpr int NC = 1000, NS = 5, NM = 10;
constexpr int NT = Bv * Tv;           // 8192 tokens

static __device__ __forceinline__ float sigmoidf_(float x) {
  return 1.f / (1.f + __expf(-x));
}

static __device__ __forceinline__ void gload_lds16(const bf16* g, bf16* l) {
  __builtin_amdgcn_global_load_lds(
      (const __attribute__((address_space(1))) void*)g,
      (__attribute__((address_space(3))) void*)l, 16, 0, 0);
}

// ---------------- m97-structure GEMM: C[M,N] = A[M,K] @ W[N,K]^T + bias -------
// 128x128 tile, BK=32, 4 waves (2x2 of 64x64), global_load_lds(16B) staging.
// transT: write C row token=b*T+t at output row t*64+b (time-major for LSTM).
__global__ __launch_bounds__(256) void gemm128(
    const bf16* __restrict__ A, const bf16* __restrict__ W,
    const float* __restrict__ bias, bf16* __restrict__ C,
    int M, int N, int K, int transT)
{
  __shared__ bf16 sa[128 * 32];
  __shared__ bf16 sb[128 * 32];
  int wave = threadIdx.x >> 6, lane = threadIdx.x & 63;
  int l15 = lane & 15, lhi = lane >> 4;
  int wr = wave >> 1, wc = wave & 1;
  int row0 = blockIdx.x * 128, col0 = blockIdx.y * 128;
  f32x4 acc[4][4];
#pragma unroll
  for (int m = 0; m < 4; ++m)
#pragma unroll
    for (int n = 0; n < 4; ++n) acc[m][n] = f32x4{0.f, 0.f, 0.f, 0.f};

  // staging: wave w, issue i covers LDS rows w*32+i*16 .. +16 (linear layout)
  int sr = wave * 32 + (lane >> 2);
  int sk = (lane & 3) * 8;
  const bf16* srcA = A + (size_t)(row0 + sr) * K + sk;
  const bf16* srcB = W + (size_t)(col0 + sr) * K + sk;
  bf16* dstA0 = &sa[wave * 1024];
  bf16* dstB0 = &sb[wave * 1024];

  for (int k0 = 0; k0 < K; k0 += 32) {
    __syncthreads();
    gload_lds16(srcA + k0,            dstA0);
    gload_lds16(srcA + 16 * K + k0,   dstA0 + 512);
    gload_lds16(srcB + k0,            dstB0);
    gload_lds16(srcB + 16 * K + k0,   dstB0 + 512);
    __syncthreads();
    bf16x8 af[4], bfr[4];
#pragma unroll
    for (int m = 0; m < 4; ++m)
      af[m] = *reinterpret_cast<const bf16x8*>(&sa[(wr * 64 + m * 16 + l15) * 32 + lhi * 8]);
#pragma unroll
    for (int n = 0; n < 4; ++n)
      bfr[n] = *reinterpret_cast<const bf16x8*>(&sb[(wc * 64 + n * 16 + l15) * 32 + lhi * 8]);
#pragma unroll
    for (int m = 0; m < 4; ++m)
#pragma unroll
      for (int n = 0; n < 4; ++n)
        acc[m][n] = __builtin_amdgcn_mfma_f32_16x16x32_bf16(af[m], bfr[n], acc[m][n], 0, 0, 0);
  }

#pragma unroll
  for (int n = 0; n < 4; ++n) {
    int col = col0 + wc * 64 + n * 16 + l15;
    float bv = bias ? bias[col] : 0.f;
#pragma unroll
    for (int m = 0; m < 4; ++m) {
#pragma unroll
      for (int r = 0; r < 4; ++r) {
        int row = row0 + wr * 64 + m * 16 + lhi * 4 + r;
        int orow = transT ? ((row & (Tv - 1)) * Bv + (row >> 7)) : row;
        C[(size_t)orow * N + col] = __float2bfloat16(acc[m][n][r] + bv);
      }
    }
  }
}

// ---------------- f32 -> bf16 convert ----------------
__global__ void f2b_kernel(const float* __restrict__ s, bf16* __restrict__ d, int n4)
{
  int i = blockIdx.x * 256 + threadIdx.x;
  if (i < n4) {
    float4 v = ((const float4*)s)[i];
    bf16* o = d + (size_t)i * 4;
    o[0] = __float2bfloat16(v.x); o[1] = __float2bfloat16(v.y);
    o[2] = __float2bfloat16(v.z); o[3] = __float2bfloat16(v.w);
  }
}

__global__ void add2_kernel(const float* __restrict__ a, const float* __restrict__ b,
                            float* __restrict__ o, int n)
{
  int i = blockIdx.x * 256 + threadIdx.x;
  if (i < n) o[i] = a[i] + b[i];
}

// ---------------- emb table: 640 distinct (t, stage) rows ----------------
__global__ __launch_bounds__(128) void emb_kernel(
    const float* __restrict__ w1, const float* __restrict__ b1,
    const float* __restrict__ g1, const float* __restrict__ bb1,
    const float* __restrict__ w2, const float* __restrict__ b2,
    const float* __restrict__ g2, const float* __restrict__ bb2,
    float* __restrict__ emb)
{
  int combo = blockIdx.x;                 // t*5 + s
  float tpos = (float)(combo / 5);
  float stg  = (float)(combo % 5);
  int tid = threadIdx.x;
  __shared__ float hb[64];
  __shared__ float rs[4];
  if (tid < 64) {
    float v = w1[tid * 2] * tpos + w1[tid * 2 + 1] * stg + b1[tid];
    float s = v, s2 = v * v;
    for (int off = 32; off; off >>= 1) { s += __shfl_down(s, off); s2 += __shfl_down(s2, off); }
    s = __shfl(s, 0); s2 = __shfl(s2, 0);
    float mu = s / 64.f, var = s2 / 64.f - mu * mu;
    float h = (v - mu) * rsqrtf(var + 1e-5f) * g1[tid] + bb1[tid];
    hb[tid] = fmaxf(h, 0.f);
  }
  __syncthreads();
  float outv[8];
  float s = 0.f, s2 = 0.f;
  int d0 = tid * 8;
#pragma unroll
  for (int o = 0; o < 8; ++o) {
    int d = d0 + o;
    float acc = b2[d];
    const float4* wr = (const float4*)(w2 + (size_t)d * 64);
#pragma unroll
    for (int k4 = 0; k4 < 16; ++k4) {
      float4 w = wr[k4];
      acc += w.x * hb[k4 * 4] + w.y * hb[k4 * 4 + 1] + w.z * hb[k4 * 4 + 2] + w.w * hb[k4 * 4 + 3];
    }
    outv[o] = acc; s += acc; s2 += acc * acc;
  }
  for (int off = 32; off; off >>= 1) { s += __shfl_down(s, off); s2 += __shfl_down(s2, off); }
  int wid = tid >> 6;
  if ((tid & 63) == 0) { rs[wid] = s; rs[2 + wid] = s2; }
  __syncthreads();
  s = rs[0] + rs[1]; s2 = rs[2] + rs[3];
  float mu = s / 1024.f, var = s2 / 1024.f - mu * mu;
  float rstd = rsqrtf(var + 1e-5f);
  float* op = emb + (size_t)combo * Dv + d0;
#pragma unroll
  for (int o = 0; o < 8; ++o) {
    int d = d0 + o;
    op[o] = (outv[o] - mu) * rstd * g2[d] + bb2[d];
  }
}

__global__ __launch_bounds__(256) void addemb_kernel(
    const float* __restrict__ x, const int* __restrict__ stage,
    const float* __restrict__ emb, bf16* __restrict__ xpe)
{
  int tok = blockIdx.x;
  int row = (tok & (Tv - 1)) * NS + stage[tok];
  const float4* xr = (const float4*)(x + (size_t)tok * Dv);
  const float4* er = (const float4*)(emb + (size_t)row * Dv);
  bf16* op = xpe + (size_t)tok * Dv + threadIdx.x * 4;
  float4 xv = xr[threadIdx.x], ev = er[threadIdx.x];
  op[0] = __float2bfloat16(xv.x + ev.x);
  op[1] = __float2bfloat16(xv.y + ev.y);
  op[2] = __float2bfloat16(xv.z + ev.z);
  op[3] = __float2bfloat16(xv.w + ev.w);
}

// ---------------- attention: per (b,h) flash-style, scalar fp32 ----------------
__global__ __launch_bounds__(256) void attn_kernel(const bf16* __restrict__ qkv,
                                                   bf16* __restrict__ o)
{
  __shared__ bf16 kl[128][128];
  __shared__ bf16 vl[128][128];
  int bh = blockIdx.x;
  int b = bh >> 3, h = bh & 7;
  int tid = threadIdx.x;
  int row = tid >> 1, hf = tid & 1;
  {
    const bf16* ks = qkv + (size_t)(b * Tv + row) * 3072 + Dv + h * HDv + hf * 64;
    const bf16* vs = ks + Dv;
    uint4* dk = (uint4*)&kl[row][hf * 64];
    uint4* dv = (uint4*)&vl[row][hf * 64];
    const uint4* sk = (const uint4*)ks;
    const uint4* sv = (const uint4*)vs;
#pragma unroll
    for (int i = 0; i < 8; ++i) { dk[i] = sk[i]; dv[i] = sv[i]; }
  }
  float qf[64];
  {
    const bf16* qs = qkv + (size_t)(b * Tv + row) * 3072 + h * HDv + hf * 64;
#pragma unroll
    for (int d2 = 0; d2 < 32; ++d2) {
      float2 f = __bfloat1622float2(*(const __hip_bfloat162*)(qs + 2 * d2));
      qf[2 * d2] = f.x; qf[2 * d2 + 1] = f.y;
    }
  }
  __syncthreads();
  float oacc[64];
#pragma unroll
  for (int d = 0; d < 64; ++d) oacc[d] = 0.f;
  float m = -1e30f, l = 0.f;
  const float scale = 0.088388347648318447f;  // 1/sqrt(128)
  for (int j = 0; j < 128; ++j) {
    float part = 0.f;
#pragma unroll
    for (int d2 = 0; d2 < 32; ++d2) {
      float2 kv2 = __bfloat1622float2(*(const __hip_bfloat162*)&kl[j][hf * 64 + 2 * d2]);
      part += qf[2 * d2] * kv2.x + qf[2 * d2 + 1] * kv2.y;
    }
    float sfull = (part + __shfl_xor(part, 1)) * scale;
    float mn = fmaxf(m, sfull);
    float al = __expf(m - mn);
    float p = __expf(sfull - mn);
    l = l * al + p;
#pragma unroll
    for (int d2 = 0; d2 < 32; ++d2) {
      float2 vv = __bfloat1622float2(*(const __hip_bfloat162*)&vl[j][hf * 64 + 2 * d2]);
      oacc[2 * d2]     = oacc[2 * d2] * al + p * vv.x;
      oacc[2 * d2 + 1] = oacc[2 * d2 + 1] * al + p * vv.y;
    }
    m = mn;
  }
  float rl = 1.f / l;
  bf16* od = o + (size_t)(b * Tv + row) * Dv + h * HDv + hf * 64;
#pragma unroll
  for (int d = 0; d < 64; ++d) od[d] = __float2bfloat16(oacc[d] * rl);
}

// ---------------- residual + LN -> raw (f32 to d_out) + raw16 -----------------
__global__ __launch_bounds__(256) void residual_ln_kernel(
    const bf16* __restrict__ xpe, const bf16* __restrict__ ao,
    const float* __restrict__ gam, const float* __restrict__ bet,
    float* __restrict__ rawf, bf16* __restrict__ raw16)
{
  int tok = blockIdx.x, tid = threadIdx.x;
  float v[4]; float s = 0.f, s2 = 0.f;
  __shared__ float rs[8];
#pragma unroll
  for (int q = 0; q < 4; ++q) {
    int d = tid + q * 256;
    size_t idx = (size_t)tok * Dv + d;
    float a = __bfloat162float(xpe[idx]) + __bfloat162float(ao[idx]);
    v[q] = a; s += a; s2 += a * a;
  }
  for (int off = 32; off; off >>= 1) { s += __shfl_down(s, off); s2 += __shfl_down(s2, off); }
  int wid = tid >> 6;
  if ((tid & 63) == 0) { rs[wid] = s; rs[4 + wid] = s2; }
  __syncthreads();
  s = rs[0] + rs[1] + rs[2] + rs[3];
  s2 = rs[4] + rs[5] + rs[6] + rs[7];
  float mu = s / 1024.f, var = s2 / 1024.f - mu * mu;
  float rstd = rsqrtf(var + 1e-5f);
#pragma unroll
  for (int q = 0; q < 4; ++q) {
    int d = tid + q * 256;
    size_t idx = (size_t)tok * Dv + d;
    float rv = (v[q] - mu) * rstd * gam[d] + bet[d];
    rawf[idx] = rv;
    raw16[idx] = __float2bfloat16(rv);
  }
}

// ---------------- persistent LSTM layer ----------------
// 64 blocks x 256 threads. block owns units u0..u0+15 (all 4 gates); wave = gate.
// Whh held in registers. h ping-pong in global, BLOCK-MAJOR layout:
// h[(u>>4)*1024 + bb*16 + (u&15)]. Grid barrier via agent-scope atomics.
__global__ __launch_bounds__(256, 1) void lstm_persistent(
    const bf16* __restrict__ Whh, const bf16* __restrict__ xgT,
    bf16* hbuf, bf16* __restrict__ y0, float* __restrict__ pooled,
    int* ctr)
{
  const int blk = blockIdx.x;
  const int u0 = blk * 16;
  const int tid = threadIdx.x;
  const int g = tid >> 6, lane = tid & 63;
  const int l15 = lane & 15, lhi = lane >> 4;

  // preload this wave's 16 Whh rows (gate g) into registers: 32 x bf16x8
  bf16x8 w[32];
  {
    const bf16* wrow = Whh + (size_t)(g * Dv + u0 + l15) * Dv;
#pragma unroll
    for (int i = 0; i < 32; ++i)
      w[i] = *reinterpret_cast<const bf16x8*>(wrow + i * 32 + lhi * 8);
  }
  __shared__ float gl[4][64][16];
  float creg[4] = {0.f, 0.f, 0.f, 0.f};
  const int pbase = tid * 4;

  for (int t = 0; t < Tv; ++t) {
    f32x4 a0 = f32x4{0.f, 0.f, 0.f, 0.f}, a1 = a0, a2 = a0, a3 = a0;
    if (t > 0) {
      const bf16* hp = hbuf + ((t - 1) & 1) * 65536;
      const int ko = (lhi & 1) * 8;
#pragma unroll
      for (int i = 0; i < 32; ++i) {
        int kb = i * 2 + (lhi >> 1);
        const bf16* hbase = hp + kb * 1024 + l15 * 16 + ko;
        bf16x8 f0 = *reinterpret_cast<const bf16x8*>(hbase);
        bf16x8 f1 = *reinterpret_cast<const bf16x8*>(hbase + 16 * 16);
        bf16x8 f2 = *reinterpret_cast<const bf16x8*>(hbase + 32 * 16);
        bf16x8 f3 = *reinterpret_cast<const bf16x8*>(hbase + 48 * 16);
        a0 = __builtin_amdgcn_mfma_f32_16x16x32_bf16(f0, w[i], a0, 0, 0, 0);
        a1 = __builtin_amdgcn_mfma_f32_16x16x32_bf16(f1, w[i], a1, 0, 0, 0);
        a2 = __builtin_amdgcn_mfma_f32_16x16x32_bf16(f2, w[i], a2, 0, 0, 0);
        a3 = __builtin_amdgcn_mfma_f32_16x16x32_bf16(f3, w[i], a3, 0, 0, 0);
      }
    }
    const bf16* xg_t = xgT + (size_t)t * (Bv * 4 * Dv) + g * Dv + u0 + l15;
#pragma unroll
    for (int m = 0; m < 4; ++m) {
      f32x4 av = (m == 0) ? a0 : (m == 1) ? a1 : (m == 2) ? a2 : a3;
#pragma unroll
      for (int r = 0; r < 4; ++r) {
        int bb = m * 16 + lhi * 4 + r;
        gl[g][bb][l15] = av[r] + __bfloat162float(xg_t[(size_t)bb * (4 * Dv)]);
      }
    }
    __syncthreads();
    bf16* hout = hbuf + (t & 1) * 65536 + blk * 1024;
#pragma unroll
    for (int q = 0; q < 4; ++q) {
      int p = pbase + q, bb = p >> 4, uu = p & 15;
      float gi = gl[0][bb][uu], gf = gl[1][bb][uu], gc = gl[2][bb][uu], go = gl[3][bb][uu];
      float cn = sigmoidf_(gf) * creg[q] + sigmoidf_(gi) * tanhf(gc);
      float hn = sigmoidf_(go) * tanhf(cn);
      creg[q] = cn;
      hout[p] = __float2bfloat16(hn);
      if (y0) y0[((size_t)bb * Tv + t) * Dv + u0 + uu] = __float2bfloat16(hn);
      if (pooled && t == Tv - 1) pooled[bb * Dv + u0 + uu] = hn;
    }
    if (t < Tv - 1) {
      __syncthreads();
      if (tid == 0) {
        __threadfence();   // release: write back h before arrive
        __hip_atomic_fetch_add(ctr, 1, __ATOMIC_RELAXED, __HIP_MEMORY_SCOPE_AGENT);
        while (__hip_atomic_load(ctr, __ATOMIC_RELAXED, __HIP_MEMORY_SCOPE_AGENT) < 64 * (t + 1))
          __builtin_amdgcn_s_sleep(2);
        __threadfence();   // acquire: invalidate stale h lines
      }
      __syncthreads();
    }
  }
}

// ---------------- raw_mean over T ----------------
__global__ void rawmean_kernel(const float* __restrict__ raw, float* __restrict__ out)
{
  int i = blockIdx.x * 256 + threadIdx.x;   // 65536
  int b = i >> 10, d = i & 1023;
  const float* r = raw + (size_t)b * Tv * Dv + d;
  float s = 0.f;
  for (int t = 0; t < Tv; ++t) s += r[(size_t)t * Dv];
  out[i] = s * (1.f / Tv);
}

// ---------------- gated fusion ----------------
__global__ __launch_bounds__(256) void gate1_kernel(
    const float* __restrict__ pooled, const float* __restrict__ rawmean,
    const float* __restrict__ w1, const float* __restrict__ b1, float* __restrict__ out)
{
  int b = blockIdx.x;
  __shared__ float cat[2048];
  for (int k = threadIdx.x; k < 1024; k += 256) {
    cat[k] = pooled[b * 1024 + k];
    cat[1024 + k] = rawmean[b * 1024 + k];
  }
  __syncthreads();
  for (int jj = 0; jj < 4; ++jj) {
    int j = threadIdx.x + jj * 256;
    float acc = b1[j];
    const float4* wr = (const float4*)(w1 + (size_t)j * 2048);
    for (int k4 = 0; k4 < 512; ++k4) {
      float4 w = wr[k4];
      acc += w.x * cat[k4 * 4] + w.y * cat[k4 * 4 + 1] + w.z * cat[k4 * 4 + 2] + w.w * cat[k4 * 4 + 3];
    }
    out[b * 1024 + j] = fmaxf(acc, 0.f);
  }
}

__global__ __launch_bounds__(256) void gate2_kernel(
    const float* __restrict__ gt1, const float* __restrict__ pooled,
    const float* __restrict__ rawmean,
    const float* __restrict__ w2, const float* __restrict__ b2, float* __restrict__ fused)
{
  int b = blockIdx.x;
  __shared__ float cl[1024];
  for (int k = threadIdx.x; k < 1024; k += 256) cl[k] = gt1[b * 1024 + k];
  __syncthreads();
  for (int jj = 0; jj < 4; ++jj) {
    int j = threadIdx.x + jj * 256;
    float acc = b2[j];
    const float4* wr = (const float4*)(w2 + (size_t)j * 1024);
    for (int k4 = 0; k4 < 256; ++k4) {
      float4 w = wr[k4];
      acc += w.x * cl[k4 * 4] + w.y * cl[k4 * 4 + 1] + w.z * cl[k4 * 4 + 2] + w.w * cl[k4 * 4 + 3];
    }
    float gv = sigmoidf_(acc);
    int idx = b * 1024 + j;
    fused[idx] = gv * pooled[idx] + (1.f - gv) * rawmean[idx];
  }
}

// ---------------- stage head ----------------
__global__ __launch_bounds__(128) void head_kernel(
    const float* __restrict__ fused,
    const float* __restrict__ w1, const float* __restrict__ b1,
    const float* __restrict__ gam, const float* __restrict__ bet,
    const float* __restrict__ w2, const float* __restrict__ b2,
    float* __restrict__ logits)
{
  int b = blockIdx.x;
  __shared__ float fl[1024];
  __shared__ float h1[512];
  __shared__ float rs[4];
  for (int k = threadIdx.x; k < 1024; k += 128) fl[k] = fused[b * 1024 + k];
  __syncthreads();
  float vals[4]; float s = 0.f, s2 = 0.f;
  for (int jj = 0; jj < 4; ++jj) {
    int j = threadIdx.x + jj * 128;
    float acc = b1[j];
    const float4* wr = (const float4*)(w1 + (size_t)j * 1024);
    for (int k4 = 0; k4 < 256; ++k4) {
      float4 w = wr[k4];
      acc += w.x * fl[k4 * 4] + w.y * fl[k4 * 4 + 1] + w.z * fl[k4 * 4 + 2] + w.w * fl[k4 * 4 + 3];
    }
    vals[jj] = acc; s += acc; s2 += acc * acc;
  }
  for (int off = 32; off; off >>= 1) { s += __shfl_down(s, off); s2 += __shfl_down(s2, off); }
  int wid = threadIdx.x >> 6;
  if ((threadIdx.x & 63) == 0) { rs[wid] = s; rs[2 + wid] = s2; }
  __syncthreads();
  s = rs[0] + rs[1]; s2 = rs[2] + rs[3];
  float mu = s / 512.f, var = s2 / 512.f - mu * mu;
  float rstd = rsqrtf(var + 1e-5f);
  for (int jj = 0; jj < 4; ++jj) {
    int j = threadIdx.x + jj * 128;
    h1[j] = fmaxf((vals[jj] - mu) * rstd * gam[j] + bet[j], 0.f);
  }
  __syncthreads();
  if (threadIdx.x < 5) {
    float acc = b2[threadIdx.x];
    for (int k = 0; k < 512; ++k) acc += h1[k] * w2[threadIdx.x * 512 + k];
    logits[b * 5 + threadIdx.x] = acc;
  }
}

// ---------------- memory bank update ----------------
__global__ void scatter_last_kernel(const int* __restrict__ cls,
                                    const int* __restrict__ stage, int* __restrict__ last)
{
  int i = blockIdx.x * 256 + threadIdx.x;
  if (i < NT) {
    int b = i >> 7;
    int p = cls[b] * NS + stage[i];
    atomicMax(&last[p], i);
  }
}

__global__ __launch_bounds__(256) void mem_update_kernel(
    const float* __restrict__ mem_in, const float* __restrict__ raw,
    const int* __restrict__ cnt_in, const int* __restrict__ last,
    float* __restrict__ mem_out, float* __restrict__ cnt_out)
{
  int p = blockIdx.x;
  int cnt = cnt_in[p];
  int li = last[p];
  bool present = li >= 0;
  bool full = cnt >= NM;
  int wp = full ? NM - 1 : cnt;
  const float* newf = raw + (size_t)(li < 0 ? 0 : li) * Dv;
  const float* src = mem_in + (size_t)p * NM * Dv;
  float* dst = mem_out + (size_t)p * NM * Dv;
  for (int idx = threadIdx.x; idx < NM * Dv / 4; idx += 256) {
    int m = idx >> 8;          // 256 float4 per row
    int dq = idx & 255;
    float4 v;
    if (present && full) {
      v = (m < NM - 1) ? *(const float4*)(src + (size_t)(m + 1) * Dv + dq * 4)
                       : *(const float4*)(newf + dq * 4);
    } else if (present) {
      v = (m == wp) ? *(const float4*)(newf + dq * 4)
                    : *(const float4*)(src + (size_t)m * Dv + dq * 4);
    } else {
      v = *(const float4*)(src + (size_t)m * Dv + dq * 4);
    }
    *(float4*)(dst + (size_t)m * Dv + dq * 4) = v;
  }
  if (threadIdx.x == 0)
    cnt_out[p] = (float)(cnt + ((present && !full) ? 1 : 0));
}

// =======================================================================
extern "C" void kernel_launch(void* const* d_in, const int* in_sizes, int n_in,
                              void* d_out, int out_size, void* d_ws, size_t ws_size,
                              hipStream_t stream)
{
  (void)in_sizes; (void)n_in; (void)out_size; (void)ws_size;
  const float* x       = (const float*)d_in[0];
  const int* stage     = (const int*)d_in[1];
  const int* cls       = (const int*)d_in[2];
  const float* enc_w1  = (const float*)d_in[3];
  const float* enc_b1  = (const float*)d_in[4];
  const float* enc_g1  = (const float*)d_in[5];
  const float* enc_bb1 = (const float*)d_in[6];
  const float* enc_w2  = (const float*)d_in[7];
  const float* enc_b2  = (const float*)d_in[8];
  const float* enc_g2  = (const float*)d_in[9];
  const float* enc_bb2 = (const float*)d_in[10];
  const float* qkv_w   = (const float*)d_in[11];
  const float* qkv_b   = (const float*)d_in[12];
  const float* out_w   = (const float*)d_in[13];
  const float* out_b   = (const float*)d_in[14];
  const float* norm_g  = (const float*)d_in[15];
  const float* norm_b  = (const float*)d_in[16];
  const float* Wih0    = (const float*)d_in[17];
  const float* Whh0    = (const float*)d_in[18];
  const float* bih0    = (const float*)d_in[19];
  const float* bhh0    = (const float*)d_in[20];
  const float* Wih1    = (const float*)d_in[21];
  const float* Whh1    = (const float*)d_in[22];
  const float* bih1    = (const float*)d_in[23];
  const float* bhh1    = (const float*)d_in[24];
  const float* head_w1 = (const float*)d_in[25];
  const float* head_b1 = (const float*)d_in[26];
  const float* head_g  = (const float*)d_in[27];
  const float* head_bb = (const float*)d_in[28];
  const float* head_w2 = (const float*)d_in[29];
  const float* head_b2 = (const float*)d_in[30];
  const float* gate_w1 = (const float*)d_in[31];
  const float* gate_b1 = (const float*)d_in[32];
  const float* gate_w2 = (const float*)d_in[33];
  const float* gate_b2 = (const float*)d_in[34];
  const float* mem_in  = (const float*)d_in[35];
  const int* cnt_in    = (const int*)d_in[36];

  float* out = (float*)d_out;
  float* out_fused  = out;                      // 65536
  float* out_raw    = out + 65536;              // 8388608
  float* out_logits = out + 8454144;            // 320
  float* out_mem    = out + 8454464;            // 51200000
  float* out_cnt    = out + 59654464;           // 5000

  // ---- workspace layout (bf16 weights + small state), ~41 MB ----
  char* wsb = (char*)d_ws;
  auto alloc = [&](size_t bytes) { char* p = wsb; wsb += (bytes + 255) & ~(size_t)255; return p; };
  bf16* wq16   = (bf16*)alloc((size_t)3072 * 1024 * 2);
  bf16* wo16   = (bf16*)alloc((size_t)1024 * 1024 * 2);
  bf16* wih0b  = (bf16*)alloc((size_t)4096 * 1024 * 2);
  bf16* whh0b  = (bf16*)alloc((size_t)4096 * 1024 * 2);
  bf16* wih1b  = (bf16*)alloc((size_t)4096 * 1024 * 2);
  bf16* whh1b  = (bf16*)alloc((size_t)4096 * 1024 * 2);
  float* bsum0 = (float*)alloc(4096 * 4);
  float* bsum1 = (float*)alloc(4096 * 4);
  bf16* hbuf   = (bf16*)alloc((size_t)2 * 65536 * 2);
  float* pooled  = (float*)alloc(65536 * 4);
  float* rawmean = (float*)alloc(65536 * 4);
  float* gt1     = (float*)alloc(65536 * 4);
  int* last      = (int*)alloc(5000 * 4);
  int* ctr       = (int*)alloc(256);

  // ---- large activation scratch inside the new_mem output slot (204.8 MB),
  //      all uses finish before mem_update overwrites it ----
  char* orb = (char*)out_mem;
  bf16* qkv16 = (bf16*)(orb + 0);            // 50,331,648 B
  bf16* y016  = (bf16*)(orb + 50331648);     // 16,777,216 B
  bf16* xgT   = (bf16*)(orb + 67108864);     // 67,108,864 B  [t][b][4096]
  bf16* xpe16 = (bf16*)(orb + 134217728);    // 16,777,216 B
  bf16* o16   = (bf16*)(orb + 150994944);    // 16,777,216 B
  bf16* ao16  = (bf16*)(orb + 167772160);    // 16,777,216 B
  bf16* raw16 = (bf16*)(orb + 184549376);    // 16,777,216 B (ends 201,326,592)
  float* embf = (float*)(orb + 201326592);   //  2,621,440 B (ends 203,948,032)

  // 1) weight conversions + bias sums
  f2b_kernel<<<3072, 256, 0, stream>>>(qkv_w, wq16, 786432);
  f2b_kernel<<<1024, 256, 0, stream>>>(out_w, wo16, 262144);
  f2b_kernel<<<4096, 256, 0, stream>>>(Wih0, wih0b, 1048576);
  f2b_kernel<<<4096, 256, 0, stream>>>(Whh0, whh0b, 1048576);
  f2b_kernel<<<4096, 256, 0, stream>>>(Wih1, wih1b, 1048576);
  f2b_kernel<<<4096, 256, 0, stream>>>(Whh1, whh1b, 1048576);
  add2_kernel<<<16, 256, 0, stream>>>(bih0, bhh0, bsum0, 4096);
  add2_kernel<<<16, 256, 0, stream>>>(bih1, bhh1, bsum1, 4096);

  // 2) encoder: 640-row emb table, then fused add -> xpe16
  emb_kernel<<<Tv * NS, 128, 0, stream>>>(enc_w1, enc_b1, enc_g1, enc_bb1,
                                          enc_w2, enc_b2, enc_g2, enc_bb2, embf);
  addemb_kernel<<<NT, 256, 0, stream>>>(x, stage, embf, xpe16);

  // 3) qkv = xpe @ qkv_w^T + b
  gemm128<<<dim3(NT / 128, 3072 / 128), 256, 0, stream>>>(xpe16, wq16, qkv_b, qkv16,
                                                          NT, 3072, Dv, 0);

  // 4) attention -> o16
  attn_kernel<<<Bv * Hv, 256, 0, stream>>>(qkv16, o16);

  // 5) out projection -> ao16
  gemm128<<<dim3(NT / 128, 1024 / 128), 256, 0, stream>>>(o16, wo16, out_b, ao16,
                                                          NT, Dv, Dv, 0);

  // 6) residual + LN -> raw (d_out) + raw16
  residual_ln_kernel<<<NT, 256, 0, stream>>>(xpe16, ao16, norm_g, norm_b, out_raw, raw16);

  // 7) LSTM layer 0: input gates (time-major), then persistent recurrence
  gemm128<<<dim3(NT / 128, 4096 / 128), 256, 0, stream>>>(raw16, wih0b, bsum0, xgT,
                                                          NT, 4096, Dv, 1);
  hipMemsetAsync(ctr, 0, 8, stream);
  lstm_persistent<<<64, 256, 0, stream>>>(whh0b, xgT, hbuf, y016, nullptr, ctr);

  // 8) LSTM layer 1
  gemm128<<<dim3(NT / 128, 4096 / 128), 256, 0, stream>>>(y016, wih1b, bsum1, xgT,
                                                          NT, 4096, Dv, 1);
  lstm_persistent<<<64, 256, 0, stream>>>(whh1b, xgT, hbuf, nullptr, pooled, ctr + 1);

  // 9) raw_mean, gated fusion, head
  rawmean_kernel<<<256, 256, 0, stream>>>(out_raw, rawmean);
  gate1_kernel<<<Bv, 256, 0, stream>>>(pooled, rawmean, gate_w1, gate_b1, gt1);
  gate2_kernel<<<Bv, 256, 0, stream>>>(gt1, pooled, rawmean, gate_w2, gate_b2, out_fused);
  head_kernel<<<Bv, 128, 0, stream>>>(out_fused, head_w1, head_b1, head_g, head_bb,
                                      head_w2, head_b2, out_logits);

  // 10) memory bank update (overwrites the scratch region last)
  hipMemsetAsync(last, 0xFF, 5000 * 4, stream);
  scatter_last_kernel<<<32, 256, 0, stream>>>(cls, stage, last);
  mem_update_kernel<<<NC * NS, 256, 0, stream>>>(mem_in, out_raw, cnt_in, last, out_mem, out_cnt);
}

// Round 3
// 6343.822 us; speedup vs baseline: 1.3575x; 1.0239x over previous
//
#include <hip/hip_runtime.h>
#include <hip/hip_bf16.h>

typedef __bf16 bf16x8 __attribute__((ext_vector_type(8)));
typedef float  f32x4  __attribute__((ext_vector_type(4)));
typedef unsigned long long u64;
using bf16 = __hip_bfloat16;

constexpr int Bv = 64, Tv = 128, Dv = 1024, Hv = 8, HDv = 128;
constexpr int NC = 1000, NS = 5, NM = 10;
constexpr int NT = Bv * Tv;           // 8192 tokens

static __device__ __forceinline__ float sigmoidf_(float x) {
  return 1.f / (1.f + __expf(-x));
}

static __device__ __forceinline__ void gload_lds16(const bf16* g, bf16* l) {
  __builtin_amdgcn_global_load_lds(
      (const __attribute__((address_space(1))) void*)g,
      (__attribute__((address_space(3))) void*)l, 16, 0, 0);
}

// ---------------- m97-structure GEMM: C[M,N] = A[M,K] @ W[N,K]^T + bias -------
// 128x128 tile, BK=32, 4 waves (2x2 of 64x64), global_load_lds(16B) staging.
// transT: write C row token=b*T+t at output row t*64+b (time-major for LSTM).
__global__ __launch_bounds__(256) void gemm128(
    const bf16* __restrict__ A, const bf16* __restrict__ W,
    const float* __restrict__ bias, bf16* __restrict__ C,
    int M, int N, int K, int transT)
{
  __shared__ bf16 sa[128 * 32];
  __shared__ bf16 sb[128 * 32];
  int wave = threadIdx.x >> 6, lane = threadIdx.x & 63;
  int l15 = lane & 15, lhi = lane >> 4;
  int wr = wave >> 1, wc = wave & 1;
  int row0 = blockIdx.x * 128, col0 = blockIdx.y * 128;
  f32x4 acc[4][4];
#pragma unroll
  for (int m = 0; m < 4; ++m)
#pragma unroll
    for (int n = 0; n < 4; ++n) acc[m][n] = f32x4{0.f, 0.f, 0.f, 0.f};

  int sr = wave * 32 + (lane >> 2);
  int sk = (lane & 3) * 8;
  const bf16* srcA = A + (size_t)(row0 + sr) * K + sk;
  const bf16* srcB = W + (size_t)(col0 + sr) * K + sk;
  bf16* dstA0 = &sa[wave * 1024];
  bf16* dstB0 = &sb[wave * 1024];

  for (int k0 = 0; k0 < K; k0 += 32) {
    __syncthreads();
    gload_lds16(srcA + k0,            dstA0);
    gload_lds16(srcA + 16 * K + k0,   dstA0 + 512);
    gload_lds16(srcB + k0,            dstB0);
    gload_lds16(srcB + 16 * K + k0,   dstB0 + 512);
    __syncthreads();
    bf16x8 af[4], bfr[4];
#pragma unroll
    for (int m = 0; m < 4; ++m)
      af[m] = *reinterpret_cast<const bf16x8*>(&sa[(wr * 64 + m * 16 + l15) * 32 + lhi * 8]);
#pragma unroll
    for (int n = 0; n < 4; ++n)
      bfr[n] = *reinterpret_cast<const bf16x8*>(&sb[(wc * 64 + n * 16 + l15) * 32 + lhi * 8]);
#pragma unroll
    for (int m = 0; m < 4; ++m)
#pragma unroll
      for (int n = 0; n < 4; ++n)
        acc[m][n] = __builtin_amdgcn_mfma_f32_16x16x32_bf16(af[m], bfr[n], acc[m][n], 0, 0, 0);
  }

#pragma unroll
  for (int n = 0; n < 4; ++n) {
    int col = col0 + wc * 64 + n * 16 + l15;
    float bv = bias ? bias[col] : 0.f;
#pragma unroll
    for (int m = 0; m < 4; ++m) {
#pragma unroll
      for (int r = 0; r < 4; ++r) {
        int row = row0 + wr * 64 + m * 16 + lhi * 4 + r;
        int orow = transT ? ((row & (Tv - 1)) * Bv + (row >> 7)) : row;
        C[(size_t)orow * N + col] = __float2bfloat16(acc[m][n][r] + bv);
      }
    }
  }
}

// ---------------- f32 -> bf16 convert ----------------
__global__ void f2b_kernel(const float* __restrict__ s, bf16* __restrict__ d, int n4)
{
  int i = blockIdx.x * 256 + threadIdx.x;
  if (i < n4) {
    float4 v = ((const float4*)s)[i];
    bf16* o = d + (size_t)i * 4;
    o[0] = __float2bfloat16(v.x); o[1] = __float2bfloat16(v.y);
    o[2] = __float2bfloat16(v.z); o[3] = __float2bfloat16(v.w);
  }
}

__global__ void add2_kernel(const float* __restrict__ a, const float* __restrict__ b,
                            float* __restrict__ o, int n)
{
  int i = blockIdx.x * 256 + threadIdx.x;
  if (i < n) o[i] = a[i] + b[i];
}

// ---------------- emb table: 640 distinct (t, stage) rows ----------------
__global__ __launch_bounds__(128) void emb_kernel(
    const float* __restrict__ w1, const float* __restrict__ b1,
    const float* __restrict__ g1, const float* __restrict__ bb1,
    const float* __restrict__ w2, const float* __restrict__ b2,
    const float* __restrict__ g2, const float* __restrict__ bb2,
    float* __restrict__ emb)
{
  int combo = blockIdx.x;                 // t*5 + s
  float tpos = (float)(combo / 5);
  float stg  = (float)(combo % 5);
  int tid = threadIdx.x;
  __shared__ float hb[64];
  __shared__ float rs[4];
  if (tid < 64) {
    float v = w1[tid * 2] * tpos + w1[tid * 2 + 1] * stg + b1[tid];
    float s = v, s2 = v * v;
    for (int off = 32; off; off >>= 1) { s += __shfl_down(s, off); s2 += __shfl_down(s2, off); }
    s = __shfl(s, 0); s2 = __shfl(s2, 0);
    float mu = s / 64.f, var = s2 / 64.f - mu * mu;
    float h = (v - mu) * rsqrtf(var + 1e-5f) * g1[tid] + bb1[tid];
    hb[tid] = fmaxf(h, 0.f);
  }
  __syncthreads();
  float outv[8];
  float s = 0.f, s2 = 0.f;
  int d0 = tid * 8;
#pragma unroll
  for (int o = 0; o < 8; ++o) {
    int d = d0 + o;
    float acc = b2[d];
    const float4* wr = (const float4*)(w2 + (size_t)d * 64);
#pragma unroll
    for (int k4 = 0; k4 < 16; ++k4) {
      float4 w = wr[k4];
      acc += w.x * hb[k4 * 4] + w.y * hb[k4 * 4 + 1] + w.z * hb[k4 * 4 + 2] + w.w * hb[k4 * 4 + 3];
    }
    outv[o] = acc; s += acc; s2 += acc * acc;
  }
  for (int off = 32; off; off >>= 1) { s += __shfl_down(s, off); s2 += __shfl_down(s2, off); }
  int wid = tid >> 6;
  if ((tid & 63) == 0) { rs[wid] = s; rs[2 + wid] = s2; }
  __syncthreads();
  s = rs[0] + rs[1]; s2 = rs[2] + rs[3];
  float mu = s / 1024.f, var = s2 / 1024.f - mu * mu;
  float rstd = rsqrtf(var + 1e-5f);
  float* op = emb + (size_t)combo * Dv + d0;
#pragma unroll
  for (int o = 0; o < 8; ++o) {
    int d = d0 + o;
    op[o] = (outv[o] - mu) * rstd * g2[d] + bb2[d];
  }
}

__global__ __launch_bounds__(256) void addemb_kernel(
    const float* __restrict__ x, const int* __restrict__ stage,
    const float* __restrict__ emb, bf16* __restrict__ xpe)
{
  int tok = blockIdx.x;
  int row = (tok & (Tv - 1)) * NS + stage[tok];
  const float4* xr = (const float4*)(x + (size_t)tok * Dv);
  const float4* er = (const float4*)(emb + (size_t)row * Dv);
  bf16* op = xpe + (size_t)tok * Dv + threadIdx.x * 4;
  float4 xv = xr[threadIdx.x], ev = er[threadIdx.x];
  op[0] = __float2bfloat16(xv.x + ev.x);
  op[1] = __float2bfloat16(xv.y + ev.y);
  op[2] = __float2bfloat16(xv.z + ev.z);
  op[3] = __float2bfloat16(xv.w + ev.w);
}

// ---------------- attention: per (b,h) flash-style, scalar fp32 ----------------
__global__ __launch_bounds__(256) void attn_kernel(const bf16* __restrict__ qkv,
                                                   bf16* __restrict__ o)
{
  __shared__ bf16 kl[128][128];
  __shared__ bf16 vl[128][128];
  int bh = blockIdx.x;
  int b = bh >> 3, h = bh & 7;
  int tid = threadIdx.x;
  int row = tid >> 1, hf = tid & 1;
  {
    const bf16* ks = qkv + (size_t)(b * Tv + row) * 3072 + Dv + h * HDv + hf * 64;
    const bf16* vs = ks + Dv;
    uint4* dk = (uint4*)&kl[row][hf * 64];
    uint4* dv = (uint4*)&vl[row][hf * 64];
    const uint4* sk = (const uint4*)ks;
    const uint4* sv = (const uint4*)vs;
#pragma unroll
    for (int i = 0; i < 8; ++i) { dk[i] = sk[i]; dv[i] = sv[i]; }
  }
  float qf[64];
  {
    const bf16* qs = qkv + (size_t)(b * Tv + row) * 3072 + h * HDv + hf * 64;
#pragma unroll
    for (int d2 = 0; d2 < 32; ++d2) {
      float2 f = __bfloat1622float2(*(const __hip_bfloat162*)(qs + 2 * d2));
      qf[2 * d2] = f.x; qf[2 * d2 + 1] = f.y;
    }
  }
  __syncthreads();
  float oacc[64];
#pragma unroll
  for (int d = 0; d < 64; ++d) oacc[d] = 0.f;
  float m = -1e30f, l = 0.f;
  const float scale = 0.088388347648318447f;  // 1/sqrt(128)
  for (int j = 0; j < 128; ++j) {
    float part = 0.f;
#pragma unroll
    for (int d2 = 0; d2 < 32; ++d2) {
      float2 kv2 = __bfloat1622float2(*(const __hip_bfloat162*)&kl[j][hf * 64 + 2 * d2]);
      part += qf[2 * d2] * kv2.x + qf[2 * d2 + 1] * kv2.y;
    }
    float sfull = (part + __shfl_xor(part, 1)) * scale;
    float mn = fmaxf(m, sfull);
    float al = __expf(m - mn);
    float p = __expf(sfull - mn);
    l = l * al + p;
#pragma unroll
    for (int d2 = 0; d2 < 32; ++d2) {
      float2 vv = __bfloat1622float2(*(const __hip_bfloat162*)&vl[j][hf * 64 + 2 * d2]);
      oacc[2 * d2]     = oacc[2 * d2] * al + p * vv.x;
      oacc[2 * d2 + 1] = oacc[2 * d2 + 1] * al + p * vv.y;
    }
    m = mn;
  }
  float rl = 1.f / l;
  bf16* od = o + (size_t)(b * Tv + row) * Dv + h * HDv + hf * 64;
#pragma unroll
  for (int d = 0; d < 64; ++d) od[d] = __float2bfloat16(oacc[d] * rl);
}

// ---------------- residual + LN -> raw (f32 to d_out) + raw16 -----------------
__global__ __launch_bounds__(256) void residual_ln_kernel(
    const bf16* __restrict__ xpe, const bf16* __restrict__ ao,
    const float* __restrict__ gam, const float* __restrict__ bet,
    float* __restrict__ rawf, bf16* __restrict__ raw16)
{
  int tok = blockIdx.x, tid = threadIdx.x;
  float v[4]; float s = 0.f, s2 = 0.f;
  __shared__ float rs[8];
#pragma unroll
  for (int q = 0; q < 4; ++q) {
    int d = tid + q * 256;
    size_t idx = (size_t)tok * Dv + d;
    float a = __bfloat162float(xpe[idx]) + __bfloat162float(ao[idx]);
    v[q] = a; s += a; s2 += a * a;
  }
  for (int off = 32; off; off >>= 1) { s += __shfl_down(s, off); s2 += __shfl_down(s2, off); }
  int wid = tid >> 6;
  if ((tid & 63) == 0) { rs[wid] = s; rs[4 + wid] = s2; }
  __syncthreads();
  s = rs[0] + rs[1] + rs[2] + rs[3];
  s2 = rs[4] + rs[5] + rs[6] + rs[7];
  float mu = s / 1024.f, var = s2 / 1024.f - mu * mu;
  float rstd = rsqrtf(var + 1e-5f);
#pragma unroll
  for (int q = 0; q < 4; ++q) {
    int d = tid + q * 256;
    size_t idx = (size_t)tok * Dv + d;
    float rv = (v[q] - mu) * rstd * gam[d] + bet[d];
    rawf[idx] = rv;
    raw16[idx] = __float2bfloat16(rv);
  }
}

// ---------------- persistent LSTM layer ----------------
// 64 blocks x 256 threads. block owns units u0..u0+15 (all 4 gates); wave = gate.
// Whh in registers; c in registers. h ping-pong in global, BLOCK-MAJOR layout
// h[(u>>4)*1024 + bb*16 + (u&15)], exchanged via agent-scope (sc1) atomics:
// write-through stores + bypass loads -> NO threadfence (no buffer_wbl2/inv).
__global__ __launch_bounds__(256, 1) void lstm_persistent(
    const bf16* __restrict__ Whh, const bf16* __restrict__ xgT,
    bf16* hbuf, bf16* __restrict__ y0, float* __restrict__ pooled,
    int* ctr)
{
  const int blk = blockIdx.x;
  const int u0 = blk * 16;
  const int tid = threadIdx.x;
  const int g = tid >> 6, lane = tid & 63;
  const int l15 = lane & 15, lhi = lane >> 4;

  // preload this wave's 16 Whh rows (gate g) into registers: 32 x bf16x8
  bf16x8 w[32];
  {
    const bf16* wrow = Whh + (size_t)(g * Dv + u0 + l15) * Dv;
#pragma unroll
    for (int i = 0; i < 32; ++i)
      w[i] = *reinterpret_cast<const bf16x8*>(wrow + i * 32 + lhi * 8);
  }
  __shared__ float gl[4][64][16];
  float creg[4] = {0.f, 0.f, 0.f, 0.f};
  const int pbase = tid * 4;

  for (int t = 0; t < Tv; ++t) {
    f32x4 a0 = f32x4{0.f, 0.f, 0.f, 0.f}, a1 = a0, a2 = a0, a3 = a0;
    if (t > 0) {
      const bf16* hp = hbuf + ((t - 1) & 1) * 65536;
      const int ko = (lhi & 1) * 8;
#pragma unroll
      for (int i = 0; i < 32; ++i) {
        int kb = i * 2 + (lhi >> 1);
        u64* hb8 = (u64*)(hp + kb * 1024 + l15 * 16 + ko);
        union { u64 q[2]; bf16x8 v; } F0, F1, F2, F3;
        F0.q[0] = __hip_atomic_load(hb8 + 0,   __ATOMIC_RELAXED, __HIP_MEMORY_SCOPE_AGENT);
        F0.q[1] = __hip_atomic_load(hb8 + 1,   __ATOMIC_RELAXED, __HIP_MEMORY_SCOPE_AGENT);
        F1.q[0] = __hip_atomic_load(hb8 + 64,  __ATOMIC_RELAXED, __HIP_MEMORY_SCOPE_AGENT);
        F1.q[1] = __hip_atomic_load(hb8 + 65,  __ATOMIC_RELAXED, __HIP_MEMORY_SCOPE_AGENT);
        F2.q[0] = __hip_atomic_load(hb8 + 128, __ATOMIC_RELAXED, __HIP_MEMORY_SCOPE_AGENT);
        F2.q[1] = __hip_atomic_load(hb8 + 129, __ATOMIC_RELAXED, __HIP_MEMORY_SCOPE_AGENT);
        F3.q[0] = __hip_atomic_load(hb8 + 192, __ATOMIC_RELAXED, __HIP_MEMORY_SCOPE_AGENT);
        F3.q[1] = __hip_atomic_load(hb8 + 193, __ATOMIC_RELAXED, __HIP_MEMORY_SCOPE_AGENT);
        a0 = __builtin_amdgcn_mfma_f32_16x16x32_bf16(F0.v, w[i], a0, 0, 0, 0);
        a1 = __builtin_amdgcn_mfma_f32_16x16x32_bf16(F1.v, w[i], a1, 0, 0, 0);
        a2 = __builtin_amdgcn_mfma_f32_16x16x32_bf16(F2.v, w[i], a2, 0, 0, 0);
        a3 = __builtin_amdgcn_mfma_f32_16x16x32_bf16(F3.v, w[i], a3, 0, 0, 0);
      }
    }
    const bf16* xg_t = xgT + (size_t)t * (Bv * 4 * Dv) + g * Dv + u0 + l15;
#pragma unroll
    for (int m = 0; m < 4; ++m) {
      f32x4 av = (m == 0) ? a0 : (m == 1) ? a1 : (m == 2) ? a2 : a3;
#pragma unroll
      for (int r = 0; r < 4; ++r) {
        int bb = m * 16 + lhi * 4 + r;
        gl[g][bb][l15] = av[r] + __bfloat162float(xg_t[(size_t)bb * (4 * Dv)]);
      }
    }
    __syncthreads();
    bf16* hout = hbuf + (t & 1) * 65536 + blk * 1024;
    union { u64 q; bf16 b4[4]; } HW;
#pragma unroll
    for (int q = 0; q < 4; ++q) {
      int p = pbase + q, bb = p >> 4, uu = p & 15;
      float gi = gl[0][bb][uu], gf = gl[1][bb][uu], gc = gl[2][bb][uu], go = gl[3][bb][uu];
      float cn = sigmoidf_(gf) * creg[q] + sigmoidf_(gi) * tanhf(gc);
      float hn = sigmoidf_(go) * tanhf(cn);
      creg[q] = cn;
      HW.b4[q] = __float2bfloat16(hn);
      if (y0) y0[((size_t)bb * Tv + t) * Dv + u0 + uu] = __float2bfloat16(hn);
      if (pooled && t == Tv - 1) pooled[bb * Dv + u0 + uu] = hn;
    }
    // write-through (sc1) store: visible at agent coherence point once vmcnt==0
    __hip_atomic_store((u64*)(hout + pbase), HW.q, __ATOMIC_RELAXED, __HIP_MEMORY_SCOPE_AGENT);
    if (t < Tv - 1) {
      asm volatile("s_waitcnt vmcnt(0)" ::: "memory");   // drain own stores pre-barrier
      __syncthreads();                                   // all waves' stores drained
      if (tid == 0) {
        __hip_atomic_fetch_add(ctr, 1, __ATOMIC_RELAXED, __HIP_MEMORY_SCOPE_AGENT);
        int target = 64 * (t + 1);
        while (__hip_atomic_load(ctr, __ATOMIC_RELAXED, __HIP_MEMORY_SCOPE_AGENT) < target)
          __builtin_amdgcn_s_sleep(2);
      }
      __syncthreads();
    }
  }
}

// ---------------- raw_mean over T ----------------
__global__ void rawmean_kernel(const float* __restrict__ raw, float* __restrict__ out)
{
  int i = blockIdx.x * 256 + threadIdx.x;   // 65536
  int b = i >> 10, d = i & 1023;
  const float* r = raw + (size_t)b * Tv * Dv + d;
  float s = 0.f;
  for (int t = 0; t < Tv; ++t) s += r[(size_t)t * Dv];
  out[i] = s * (1.f / Tv);
}

// ---------------- gated fusion ----------------
__global__ __launch_bounds__(256) void gate1_kernel(
    const float* __restrict__ pooled, const float* __restrict__ rawmean,
    const float* __restrict__ w1, const float* __restrict__ b1, float* __restrict__ out)
{
  int b = blockIdx.x;
  __shared__ float cat[2048];
  for (int k = threadIdx.x; k < 1024; k += 256) {
    cat[k] = pooled[b * 1024 + k];
    cat[1024 + k] = rawmean[b * 1024 + k];
  }
  __syncthreads();
  for (int jj = 0; jj < 4; ++jj) {
    int j = threadIdx.x + jj * 256;
    float acc = b1[j];
    const float4* wr = (const float4*)(w1 + (size_t)j * 2048);
    for (int k4 = 0; k4 < 512; ++k4) {
      float4 w = wr[k4];
      acc += w.x * cat[k4 * 4] + w.y * cat[k4 * 4 + 1] + w.z * cat[k4 * 4 + 2] + w.w * cat[k4 * 4 + 3];
    }
    out[b * 1024 + j] = fmaxf(acc, 0.f);
  }
}

__global__ __launch_bounds__(256) void gate2_kernel(
    const float* __restrict__ gt1, const float* __restrict__ pooled,
    const float* __restrict__ rawmean,
    const float* __restrict__ w2, const float* __restrict__ b2, float* __restrict__ fused)
{
  int b = blockIdx.x;
  __shared__ float cl[1024];
  for (int k = threadIdx.x; k < 1024; k += 256) cl[k] = gt1[b * 1024 + k];
  __syncthreads();
  for (int jj = 0; jj < 4; ++jj) {
    int j = threadIdx.x + jj * 256;
    float acc = b2[j];
    const float4* wr = (const float4*)(w2 + (size_t)j * 1024);
    for (int k4 = 0; k4 < 256; ++k4) {
      float4 w = wr[k4];
      acc += w.x * cl[k4 * 4] + w.y * cl[k4 * 4 + 1] + w.z * cl[k4 * 4 + 2] + w.w * cl[k4 * 4 + 3];
    }
    float gv = sigmoidf_(acc);
    int idx = b * 1024 + j;
    fused[idx] = gv * pooled[idx] + (1.f - gv) * rawmean[idx];
  }
}

// ---------------- stage head ----------------
__global__ __launch_bounds__(128) void head_kernel(
    const float* __restrict__ fused,
    const float* __restrict__ w1, const float* __restrict__ b1,
    const float* __restrict__ gam, const float* __restrict__ bet,
    const float* __restrict__ w2, const float* __restrict__ b2,
    float* __restrict__ logits)
{
  int b = blockIdx.x;
  __shared__ float fl[1024];
  __shared__ float h1[512];
  __shared__ float rs[4];
  for (int k = threadIdx.x; k < 1024; k += 128) fl[k] = fused[b * 1024 + k];
  __syncthreads();
  float vals[4]; float s = 0.f, s2 = 0.f;
  for (int jj = 0; jj < 4; ++jj) {
    int j = threadIdx.x + jj * 128;
    float acc = b1[j];
    const float4* wr = (const float4*)(w1 + (size_t)j * 1024);
    for (int k4 = 0; k4 < 256; ++k4) {
      float4 w = wr[k4];
      acc += w.x * fl[k4 * 4] + w.y * fl[k4 * 4 + 1] + w.z * fl[k4 * 4 + 2] + w.w * fl[k4 * 4 + 3];
    }
    vals[jj] = acc; s += acc; s2 += acc * acc;
  }
  for (int off = 32; off; off >>= 1) { s += __shfl_down(s, off); s2 += __shfl_down(s2, off); }
  int wid = threadIdx.x >> 6;
  if ((threadIdx.x & 63) == 0) { rs[wid] = s; rs[2 + wid] = s2; }
  __syncthreads();
  s = rs[0] + rs[1]; s2 = rs[2] + rs[3];
  float mu = s / 512.f, var = s2 / 512.f - mu * mu;
  float rstd = rsqrtf(var + 1e-5f);
  for (int jj = 0; jj < 4; ++jj) {
    int j = threadIdx.x + jj * 128;
    h1[j] = fmaxf((vals[jj] - mu) * rstd * gam[j] + bet[j], 0.f);
  }
  __syncthreads();
  if (threadIdx.x < 5) {
    float acc = b2[threadIdx.x];
    for (int k = 0; k < 512; ++k) acc += h1[k] * w2[threadIdx.x * 512 + k];
    logits[b * 5 + threadIdx.x] = acc;
  }
}

// ---------------- memory bank update ----------------
__global__ void scatter_last_kernel(const int* __restrict__ cls,
                                    const int* __restrict__ stage, int* __restrict__ last)
{
  int i = blockIdx.x * 256 + threadIdx.x;
  if (i < NT) {
    int b = i >> 7;
    int p = cls[b] * NS + stage[i];
    atomicMax(&last[p], i);
  }
}

__global__ __launch_bounds__(256) void mem_update_kernel(
    const float* __restrict__ mem_in, const float* __restrict__ raw,
    const int* __restrict__ cnt_in, const int* __restrict__ last,
    float* __restrict__ mem_out, float* __restrict__ cnt_out)
{
  int p = blockIdx.x;
  int cnt = cnt_in[p];
  int li = last[p];
  bool present = li >= 0;
  bool full = cnt >= NM;
  int wp = full ? NM - 1 : cnt;
  const float* newf = raw + (size_t)(li < 0 ? 0 : li) * Dv;
  const float* src = mem_in + (size_t)p * NM * Dv;
  float* dst = mem_out + (size_t)p * NM * Dv;
  for (int idx = threadIdx.x; idx < NM * Dv / 4; idx += 256) {
    int m = idx >> 8;          // 256 float4 per row
    int dq = idx & 255;
    float4 v;
    if (present && full) {
      v = (m < NM - 1) ? *(const float4*)(src + (size_t)(m + 1) * Dv + dq * 4)
                       : *(const float4*)(newf + dq * 4);
    } else if (present) {
      v = (m == wp) ? *(const float4*)(newf + dq * 4)
                    : *(const float4*)(src + (size_t)m * Dv + dq * 4);
    } else {
      v = *(const float4*)(src + (size_t)m * Dv + dq * 4);
    }
    *(float4*)(dst + (size_t)m * Dv + dq * 4) = v;
  }
  if (threadIdx.x == 0)
    cnt_out[p] = (float)(cnt + ((present && !full) ? 1 : 0));
}

// =======================================================================
extern "C" void kernel_launch(void* const* d_in, const int* in_sizes, int n_in,
                              void* d_out, int out_size, void* d_ws, size_t ws_size,
                              hipStream_t stream)
{
  (void)in_sizes; (void)n_in; (void)out_size; (void)ws_size;
  const float* x       = (const float*)d_in[0];
  const int* stage     = (const int*)d_in[1];
  const int* cls       = (const int*)d_in[2];
  const float* enc_w1  = (const float*)d_in[3];
  const float* enc_b1  = (const float*)d_in[4];
  const float* enc_g1  = (const float*)d_in[5];
  const float* enc_bb1 = (const float*)d_in[6];
  const float* enc_w2  = (const float*)d_in[7];
  const float* enc_b2  = (const float*)d_in[8];
  const float* enc_g2  = (const float*)d_in[9];
  const float* enc_bb2 = (const float*)d_in[10];
  const float* qkv_w   = (const float*)d_in[11];
  const float* qkv_b   = (const float*)d_in[12];
  const float* out_w   = (const float*)d_in[13];
  const float* out_b   = (const float*)d_in[14];
  const float* norm_g  = (const float*)d_in[15];
  const float* norm_b  = (const float*)d_in[16];
  const float* Wih0    = (const float*)d_in[17];
  const float* Whh0    = (const float*)d_in[18];
  const float* bih0    = (const float*)d_in[19];
  const float* bhh0    = (const float*)d_in[20];
  const float* Wih1    = (const float*)d_in[21];
  const float* Whh1    = (const float*)d_in[22];
  const float* bih1    = (const float*)d_in[23];
  const float* bhh1    = (const float*)d_in[24];
  const float* head_w1 = (const float*)d_in[25];
  const float* head_b1 = (const float*)d_in[26];
  const float* head_g  = (const float*)d_in[27];
  const float* head_bb = (const float*)d_in[28];
  const float* head_w2 = (const float*)d_in[29];
  const float* head_b2 = (const float*)d_in[30];
  const float* gate_w1 = (const float*)d_in[31];
  const float* gate_b1 = (const float*)d_in[32];
  const float* gate_w2 = (const float*)d_in[33];
  const float* gate_b2 = (const float*)d_in[34];
  const float* mem_in  = (const float*)d_in[35];
  const int* cnt_in    = (const int*)d_in[36];

  float* out = (float*)d_out;
  float* out_fused  = out;                      // 65536
  float* out_raw    = out + 65536;              // 8388608
  float* out_logits = out + 8454144;            // 320
  float* out_mem    = out + 8454464;            // 51200000
  float* out_cnt    = out + 59654464;           // 5000

  // ---- workspace layout (bf16 weights + small state), ~41 MB ----
  char* wsb = (char*)d_ws;
  auto alloc = [&](size_t bytes) { char* p = wsb; wsb += (bytes + 255) & ~(size_t)255; return p; };
  bf16* wq16   = (bf16*)alloc((size_t)3072 * 1024 * 2);
  bf16* wo16   = (bf16*)alloc((size_t)1024 * 1024 * 2);
  bf16* wih0b  = (bf16*)alloc((size_t)4096 * 1024 * 2);
  bf16* whh0b  = (bf16*)alloc((size_t)4096 * 1024 * 2);
  bf16* wih1b  = (bf16*)alloc((size_t)4096 * 1024 * 2);
  bf16* whh1b  = (bf16*)alloc((size_t)4096 * 1024 * 2);
  float* bsum0 = (float*)alloc(4096 * 4);
  float* bsum1 = (float*)alloc(4096 * 4);
  bf16* hbuf   = (bf16*)alloc((size_t)2 * 65536 * 2);
  float* pooled  = (float*)alloc(65536 * 4);
  float* rawmean = (float*)alloc(65536 * 4);
  float* gt1     = (float*)alloc(65536 * 4);
  int* last      = (int*)alloc(5000 * 4);
  int* ctr       = (int*)alloc(256);

  // ---- large activation scratch inside the new_mem output slot (204.8 MB),
  //      all uses finish before mem_update overwrites it ----
  char* orb = (char*)out_mem;
  bf16* qkv16 = (bf16*)(orb + 0);            // 50,331,648 B
  bf16* y016  = (bf16*)(orb + 50331648);     // 16,777,216 B
  bf16* xgT   = (bf16*)(orb + 67108864);     // 67,108,864 B  [t][b][4096]
  bf16* xpe16 = (bf16*)(orb + 134217728);    // 16,777,216 B
  bf16* o16   = (bf16*)(orb + 150994944);    // 16,777,216 B
  bf16* ao16  = (bf16*)(orb + 167772160);    // 16,777,216 B
  bf16* raw16 = (bf16*)(orb + 184549376);    // 16,777,216 B (ends 201,326,592)
  float* embf = (float*)(orb + 201326592);   //  2,621,440 B (ends 203,948,032)

  // 1) weight conversions + bias sums
  f2b_kernel<<<3072, 256, 0, stream>>>(qkv_w, wq16, 786432);
  f2b_kernel<<<1024, 256, 0, stream>>>(out_w, wo16, 262144);
  f2b_kernel<<<4096, 256, 0, stream>>>(Wih0, wih0b, 1048576);
  f2b_kernel<<<4096, 256, 0, stream>>>(Whh0, whh0b, 1048576);
  f2b_kernel<<<4096, 256, 0, stream>>>(Wih1, wih1b, 1048576);
  f2b_kernel<<<4096, 256, 0, stream>>>(Whh1, whh1b, 1048576);
  add2_kernel<<<16, 256, 0, stream>>>(bih0, bhh0, bsum0, 4096);
  add2_kernel<<<16, 256, 0, stream>>>(bih1, bhh1, bsum1, 4096);

  // 2) encoder: 640-row emb table, then fused add -> xpe16
  emb_kernel<<<Tv * NS, 128, 0, stream>>>(enc_w1, enc_b1, enc_g1, enc_bb1,
                                          enc_w2, enc_b2, enc_g2, enc_bb2, embf);
  addemb_kernel<<<NT, 256, 0, stream>>>(x, stage, embf, xpe16);

  // 3) qkv = xpe @ qkv_w^T + b
  gemm128<<<dim3(NT / 128, 3072 / 128), 256, 0, stream>>>(xpe16, wq16, qkv_b, qkv16,
                                                          NT, 3072, Dv, 0);

  // 4) attention -> o16
  attn_kernel<<<Bv * Hv, 256, 0, stream>>>(qkv16, o16);

  // 5) out projection -> ao16
  gemm128<<<dim3(NT / 128, 1024 / 128), 256, 0, stream>>>(o16, wo16, out_b, ao16,
                                                          NT, Dv, Dv, 0);

  // 6) residual + LN -> raw (d_out) + raw16
  residual_ln_kernel<<<NT, 256, 0, stream>>>(xpe16, ao16, norm_g, norm_b, out_raw, raw16);

  // 7) LSTM layer 0: input gates (time-major), then persistent recurrence
  gemm128<<<dim3(NT / 128, 4096 / 128), 256, 0, stream>>>(raw16, wih0b, bsum0, xgT,
                                                          NT, 4096, Dv, 1);
  hipMemsetAsync(ctr, 0, 8, stream);
  lstm_persistent<<<64, 256, 0, stream>>>(whh0b, xgT, hbuf, y016, nullptr, ctr);

  // 8) LSTM layer 1
  gemm128<<<dim3(NT / 128, 4096 / 128), 256, 0, stream>>>(y016, wih1b, bsum1, xgT,
                                                          NT, 4096, Dv, 1);
  lstm_persistent<<<64, 256, 0, stream>>>(whh1b, xgT, hbuf, nullptr, pooled, ctr + 1);

  // 9) raw_mean, gated fusion, head
  rawmean_kernel<<<256, 256, 0, stream>>>(out_raw, rawmean);
  gate1_kernel<<<Bv, 256, 0, stream>>>(pooled, rawmean, gate_w1, gate_b1, gt1);
  gate2_kernel<<<Bv, 256, 0, stream>>>(gt1, pooled, rawmean, gate_w2, gate_b2, out_fused);
  head_kernel<<<Bv, 128, 0, stream>>>(out_fused, head_w1, head_b1, head_g, head_bb,
                                      head_w2, head_b2, out_logits);

  // 10) memory bank update (overwrites the scratch region last)
  hipMemsetAsync(last, 0xFF, 5000 * 4, stream);
  scatter_last_kernel<<<32, 256, 0, stream>>>(cls, stage, last);
  mem_update_kernel<<<NC * NS, 256, 0, stream>>>(mem_in, out_raw, cnt_in, last, out_mem, out_cnt);
}

// Round 4
// 3469.537 us; speedup vs baseline: 2.4820x; 1.8284x over previous
//
#include <hip/hip_runtime.h>
#include <hip/hip_bf16.h>

typedef __bf16 bf16x8 __attribute__((ext_vector_type(8)));
typedef float  f32x4  __attribute__((ext_vector_type(4)));
typedef unsigned long long u64;
using bf16 = __hip_bfloat16;

constexpr int Bv = 64, Tv = 128, Dv = 1024, Hv = 8, HDv = 128;
constexpr int NC = 1000, NS = 5, NM = 10;
constexpr int NT = Bv * Tv;           // 8192 tokens

static __device__ __forceinline__ float sigmoidf_(float x) {
  return 1.f / (1.f + __expf(-x));
}

static __device__ __forceinline__ void gload_lds16(const bf16* g, bf16* l) {
  __builtin_amdgcn_global_load_lds(
      (const __attribute__((address_space(1))) void*)g,
      (__attribute__((address_space(3))) void*)l, 16, 0, 0);
}

// ---------------- m97-structure GEMM: C[M,N] = A[M,K] @ W[N,K]^T + bias -------
// 128x128 tile, BK=32, 4 waves (2x2 of 64x64), global_load_lds(16B) staging.
// transT: write C row token=b*T+t at output row t*64+b (time-major for LSTM).
__global__ __launch_bounds__(256) void gemm128(
    const bf16* __restrict__ A, const bf16* __restrict__ W,
    const float* __restrict__ bias, bf16* __restrict__ C,
    int M, int N, int K, int transT)
{
  __shared__ bf16 sa[128 * 32];
  __shared__ bf16 sb[128 * 32];
  int wave = threadIdx.x >> 6, lane = threadIdx.x & 63;
  int l15 = lane & 15, lhi = lane >> 4;
  int wr = wave >> 1, wc = wave & 1;
  int row0 = blockIdx.x * 128, col0 = blockIdx.y * 128;
  f32x4 acc[4][4];
#pragma unroll
  for (int m = 0; m < 4; ++m)
#pragma unroll
    for (int n = 0; n < 4; ++n) acc[m][n] = f32x4{0.f, 0.f, 0.f, 0.f};

  int sr = wave * 32 + (lane >> 2);
  int sk = (lane & 3) * 8;
  const bf16* srcA = A + (size_t)(row0 + sr) * K + sk;
  const bf16* srcB = W + (size_t)(col0 + sr) * K + sk;
  bf16* dstA0 = &sa[wave * 1024];
  bf16* dstB0 = &sb[wave * 1024];

  for (int k0 = 0; k0 < K; k0 += 32) {
    __syncthreads();
    gload_lds16(srcA + k0,            dstA0);
    gload_lds16(srcA + 16 * K + k0,   dstA0 + 512);
    gload_lds16(srcB + k0,            dstB0);
    gload_lds16(srcB + 16 * K + k0,   dstB0 + 512);
    __syncthreads();
    bf16x8 af[4], bfr[4];
#pragma unroll
    for (int m = 0; m < 4; ++m)
      af[m] = *reinterpret_cast<const bf16x8*>(&sa[(wr * 64 + m * 16 + l15) * 32 + lhi * 8]);
#pragma unroll
    for (int n = 0; n < 4; ++n)
      bfr[n] = *reinterpret_cast<const bf16x8*>(&sb[(wc * 64 + n * 16 + l15) * 32 + lhi * 8]);
#pragma unroll
    for (int m = 0; m < 4; ++m)
#pragma unroll
      for (int n = 0; n < 4; ++n)
        acc[m][n] = __builtin_amdgcn_mfma_f32_16x16x32_bf16(af[m], bfr[n], acc[m][n], 0, 0, 0);
  }

#pragma unroll
  for (int n = 0; n < 4; ++n) {
    int col = col0 + wc * 64 + n * 16 + l15;
    float bv = bias ? bias[col] : 0.f;
#pragma unroll
    for (int m = 0; m < 4; ++m) {
#pragma unroll
      for (int r = 0; r < 4; ++r) {
        int row = row0 + wr * 64 + m * 16 + lhi * 4 + r;
        int orow = transT ? ((row & (Tv - 1)) * Bv + (row >> 7)) : row;
        C[(size_t)orow * N + col] = __float2bfloat16(acc[m][n][r] + bv);
      }
    }
  }
}

// ---------------- f32 -> bf16 convert ----------------
__global__ void f2b_kernel(const float* __restrict__ s, bf16* __restrict__ d, int n4)
{
  int i = blockIdx.x * 256 + threadIdx.x;
  if (i < n4) {
    float4 v = ((const float4*)s)[i];
    bf16* o = d + (size_t)i * 4;
    o[0] = __float2bfloat16(v.x); o[1] = __float2bfloat16(v.y);
    o[2] = __float2bfloat16(v.z); o[3] = __float2bfloat16(v.w);
  }
}

__global__ void add2_kernel(const float* __restrict__ a, const float* __restrict__ b,
                            float* __restrict__ o, int n)
{
  int i = blockIdx.x * 256 + threadIdx.x;
  if (i < n) o[i] = a[i] + b[i];
}

// ---------------- emb table: 640 distinct (t, stage) rows ----------------
__global__ __launch_bounds__(128) void emb_kernel(
    const float* __restrict__ w1, const float* __restrict__ b1,
    const float* __restrict__ g1, const float* __restrict__ bb1,
    const float* __restrict__ w2, const float* __restrict__ b2,
    const float* __restrict__ g2, const float* __restrict__ bb2,
    float* __restrict__ emb)
{
  int combo = blockIdx.x;                 // t*5 + s
  float tpos = (float)(combo / 5);
  float stg  = (float)(combo % 5);
  int tid = threadIdx.x;
  __shared__ float hb[64];
  __shared__ float rs[4];
  if (tid < 64) {
    float v = w1[tid * 2] * tpos + w1[tid * 2 + 1] * stg + b1[tid];
    float s = v, s2 = v * v;
    for (int off = 32; off; off >>= 1) { s += __shfl_down(s, off); s2 += __shfl_down(s2, off); }
    s = __shfl(s, 0); s2 = __shfl(s2, 0);
    float mu = s / 64.f, var = s2 / 64.f - mu * mu;
    float h = (v - mu) * rsqrtf(var + 1e-5f) * g1[tid] + bb1[tid];
    hb[tid] = fmaxf(h, 0.f);
  }
  __syncthreads();
  float outv[8];
  float s = 0.f, s2 = 0.f;
  int d0 = tid * 8;
#pragma unroll
  for (int o = 0; o < 8; ++o) {
    int d = d0 + o;
    float acc = b2[d];
    const float4* wr = (const float4*)(w2 + (size_t)d * 64);
#pragma unroll
    for (int k4 = 0; k4 < 16; ++k4) {
      float4 w = wr[k4];
      acc += w.x * hb[k4 * 4] + w.y * hb[k4 * 4 + 1] + w.z * hb[k4 * 4 + 2] + w.w * hb[k4 * 4 + 3];
    }
    outv[o] = acc; s += acc; s2 += acc * acc;
  }
  for (int off = 32; off; off >>= 1) { s += __shfl_down(s, off); s2 += __shfl_down(s2, off); }
  int wid = tid >> 6;
  if ((tid & 63) == 0) { rs[wid] = s; rs[2 + wid] = s2; }
  __syncthreads();
  s = rs[0] + rs[1]; s2 = rs[2] + rs[3];
  float mu = s / 1024.f, var = s2 / 1024.f - mu * mu;
  float rstd = rsqrtf(var + 1e-5f);
  float* op = emb + (size_t)combo * Dv + d0;
#pragma unroll
  for (int o = 0; o < 8; ++o) {
    int d = d0 + o;
    op[o] = (outv[o] - mu) * rstd * g2[d] + bb2[d];
  }
}

__global__ __launch_bounds__(256) void addemb_kernel(
    const float* __restrict__ x, const int* __restrict__ stage,
    const float* __restrict__ emb, bf16* __restrict__ xpe)
{
  int tok = blockIdx.x;
  int row = (tok & (Tv - 1)) * NS + stage[tok];
  const float4* xr = (const float4*)(x + (size_t)tok * Dv);
  const float4* er = (const float4*)(emb + (size_t)row * Dv);
  bf16* op = xpe + (size_t)tok * Dv + threadIdx.x * 4;
  float4 xv = xr[threadIdx.x], ev = er[threadIdx.x];
  op[0] = __float2bfloat16(xv.x + ev.x);
  op[1] = __float2bfloat16(xv.y + ev.y);
  op[2] = __float2bfloat16(xv.z + ev.z);
  op[3] = __float2bfloat16(xv.w + ev.w);
}

// ---------------- attention: per (b,h) flash-style, scalar fp32 ----------------
__global__ __launch_bounds__(256) void attn_kernel(const bf16* __restrict__ qkv,
                                                   bf16* __restrict__ o)
{
  __shared__ bf16 kl[128][128];
  __shared__ bf16 vl[128][128];
  int bh = blockIdx.x;
  int b = bh >> 3, h = bh & 7;
  int tid = threadIdx.x;
  int row = tid >> 1, hf = tid & 1;
  {
    const bf16* ks = qkv + (size_t)(b * Tv + row) * 3072 + Dv + h * HDv + hf * 64;
    const bf16* vs = ks + Dv;
    uint4* dk = (uint4*)&kl[row][hf * 64];
    uint4* dv = (uint4*)&vl[row][hf * 64];
    const uint4* sk = (const uint4*)ks;
    const uint4* sv = (const uint4*)vs;
#pragma unroll
    for (int i = 0; i < 8; ++i) { dk[i] = sk[i]; dv[i] = sv[i]; }
  }
  float qf[64];
  {
    const bf16* qs = qkv + (size_t)(b * Tv + row) * 3072 + h * HDv + hf * 64;
#pragma unroll
    for (int d2 = 0; d2 < 32; ++d2) {
      float2 f = __bfloat1622float2(*(const __hip_bfloat162*)(qs + 2 * d2));
      qf[2 * d2] = f.x; qf[2 * d2 + 1] = f.y;
    }
  }
  __syncthreads();
  float oacc[64];
#pragma unroll
  for (int d = 0; d < 64; ++d) oacc[d] = 0.f;
  float m = -1e30f, l = 0.f;
  const float scale = 0.088388347648318447f;  // 1/sqrt(128)
  for (int j = 0; j < 128; ++j) {
    float part = 0.f;
#pragma unroll
    for (int d2 = 0; d2 < 32; ++d2) {
      float2 kv2 = __bfloat1622float2(*(const __hip_bfloat162*)&kl[j][hf * 64 + 2 * d2]);
      part += qf[2 * d2] * kv2.x + qf[2 * d2 + 1] * kv2.y;
    }
    float sfull = (part + __shfl_xor(part, 1)) * scale;
    float mn = fmaxf(m, sfull);
    float al = __expf(m - mn);
    float p = __expf(sfull - mn);
    l = l * al + p;
#pragma unroll
    for (int d2 = 0; d2 < 32; ++d2) {
      float2 vv = __bfloat1622float2(*(const __hip_bfloat162*)&vl[j][hf * 64 + 2 * d2]);
      oacc[2 * d2]     = oacc[2 * d2] * al + p * vv.x;
      oacc[2 * d2 + 1] = oacc[2 * d2 + 1] * al + p * vv.y;
    }
    m = mn;
  }
  float rl = 1.f / l;
  bf16* od = o + (size_t)(b * Tv + row) * Dv + h * HDv + hf * 64;
#pragma unroll
  for (int d = 0; d < 64; ++d) od[d] = __float2bfloat16(oacc[d] * rl);
}

// ---------------- residual + LN -> raw (f32 to d_out) + raw16 -----------------
__global__ __launch_bounds__(256) void residual_ln_kernel(
    const bf16* __restrict__ xpe, const bf16* __restrict__ ao,
    const float* __restrict__ gam, const float* __restrict__ bet,
    float* __restrict__ rawf, bf16* __restrict__ raw16)
{
  int tok = blockIdx.x, tid = threadIdx.x;
  float v[4]; float s = 0.f, s2 = 0.f;
  __shared__ float rs[8];
#pragma unroll
  for (int q = 0; q < 4; ++q) {
    int d = tid + q * 256;
    size_t idx = (size_t)tok * Dv + d;
    float a = __bfloat162float(xpe[idx]) + __bfloat162float(ao[idx]);
    v[q] = a; s += a; s2 += a * a;
  }
  for (int off = 32; off; off >>= 1) { s += __shfl_down(s, off); s2 += __shfl_down(s2, off); }
  int wid = tid >> 6;
  if ((tid & 63) == 0) { rs[wid] = s; rs[4 + wid] = s2; }
  __syncthreads();
  s = rs[0] + rs[1] + rs[2] + rs[3];
  s2 = rs[4] + rs[5] + rs[6] + rs[7];
  float mu = s / 1024.f, var = s2 / 1024.f - mu * mu;
  float rstd = rsqrtf(var + 1e-5f);
#pragma unroll
  for (int q = 0; q < 4; ++q) {
    int d = tid + q * 256;
    size_t idx = (size_t)tok * Dv + d;
    float rv = (v[q] - mu) * rstd * gam[d] + bet[d];
    rawf[idx] = rv;
    raw16[idx] = __float2bfloat16(rv);
  }
}

// ---------------- persistent LSTM: 4 batch-groups x 64 unit-blocks ------------
// Grid 256 blocks x 256 threads. Block (gid, j): batches gid*16..+15, units
// j*16..+15 (all 4 gates; wave = gate). Per step: stage group h [16,1024] into
// LDS once (8B agent-scope loads), MFMA [16,1024]@[1024,16] per wave, gate
// nonlin, sc1-store h chunk [16,16], flag barrier (own-flag store + 64-flag
// poll; no atomic RMW). Double-buffered h; WAR-safe (see analysis).
__global__ __launch_bounds__(256, 1) void lstm_seq(
    const bf16* __restrict__ Whh, const bf16* __restrict__ xgT,
    bf16* hbuf,                // 4 groups * 2 * 16384 bf16
    bf16* __restrict__ y0, float* __restrict__ pooled,
    int* flags)                // 4 groups * 64 ints, pre-zeroed
{
  const int gid = blockIdx.x >> 6;     // batch group
  const int j   = blockIdx.x & 63;     // unit block
  const int u0  = j * 16;
  const int tid = threadIdx.x;
  const int g = tid >> 6, lane = tid & 63;
  const int l15 = lane & 15, lhi = lane >> 4;

  // preload this wave's 16 Whh rows (gate g, units u0..u0+15): 32 x bf16x8
  bf16x8 w[32];
  {
    const bf16* wrow = Whh + (size_t)(g * Dv + u0 + l15) * Dv;
#pragma unroll
    for (int i = 0; i < 32; ++i)
      w[i] = *reinterpret_cast<const bf16x8*>(wrow + i * 32 + lhi * 8);
  }

  __shared__ bf16 hlds[16 * 1032];     // group h, +8 pad per row (bank spread)
  __shared__ float gl[4][16][16];
  __shared__ bf16 hstage[16 * 16];

  float creg = 0.f;
  const int bb_t = tid >> 4, uu_t = tid & 15;

  bf16* hgrp = hbuf + (size_t)gid * 32768;
  int* gflags = flags + gid * 64;

  for (int t = 0; t < Tv; ++t) {
    f32x4 acc = f32x4{0.f, 0.f, 0.f, 0.f};
    if (t > 0) {
      // stage h(t-1) [16,1024] -> LDS via agent-scope (L1/L2-bypass) loads
      const u64* hsrc = (const u64*)(hgrp + ((t - 1) & 1) * 16384);
      u64* hldsq = (u64*)hlds;
#pragma unroll
      for (int it = 0; it < 16; ++it) {
        int idx = it * 256 + tid;            // 4096 u64 total
        int bb = idx >> 8, kk = idx & 255;   // 256 u64 per 1024-elem row
        u64 v = __hip_atomic_load(hsrc + idx, __ATOMIC_RELAXED, __HIP_MEMORY_SCOPE_AGENT);
        hldsq[bb * 258 + kk] = v;            // row stride 1032 bf16 = 258 u64
      }
      __syncthreads();
#pragma unroll
      for (int k0 = 0; k0 < 32; ++k0) {
        bf16x8 a = *reinterpret_cast<const bf16x8*>(&hlds[l15 * 1032 + k0 * 32 + lhi * 8]);
        acc = __builtin_amdgcn_mfma_f32_16x16x32_bf16(a, w[k0], acc, 0, 0, 0);
      }
    }
    // add xg, expose all 4 gates via LDS
    const bf16* xg_t = xgT + (size_t)t * (Bv * 4 * Dv) + (size_t)(gid * 16) * (4 * Dv)
                       + g * Dv + u0 + l15;
#pragma unroll
    for (int r = 0; r < 4; ++r) {
      int bb = lhi * 4 + r;
      gl[g][bb][l15] = acc[r] + __bfloat162float(xg_t[(size_t)bb * (4 * Dv)]);
    }
    __syncthreads();
    // gate nonlinearity + c/h update: one (batch, unit) per thread
    {
      float gi = gl[0][bb_t][uu_t], gf = gl[1][bb_t][uu_t];
      float gc = gl[2][bb_t][uu_t], go = gl[3][bb_t][uu_t];
      float cn = sigmoidf_(gf) * creg + sigmoidf_(gi) * tanhf(gc);
      float hn = sigmoidf_(go) * tanhf(cn);
      creg = cn;
      hstage[bb_t * 16 + uu_t] = __float2bfloat16(hn);
      if (y0) y0[((size_t)(gid * 16 + bb_t) * Tv + t) * Dv + u0 + uu_t] = __float2bfloat16(hn);
      if (pooled && t == Tv - 1) pooled[(gid * 16 + bb_t) * Dv + u0 + uu_t] = hn;
    }
    __syncthreads();
    // sc1-store h chunk [16 rows x 16 units] (wave 0: 64 x 8B)
    bf16* hdst = hgrp + (t & 1) * 16384;
    if (tid < 64) {
      int bb = tid >> 2, seg = tid & 3;
      u64 v = ((u64*)hstage)[bb * 4 + seg];
      __hip_atomic_store((u64*)(hdst + bb * Dv + u0) + seg, v,
                         __ATOMIC_RELAXED, __HIP_MEMORY_SCOPE_AGENT);
    }
    if (t < Tv - 1) {
      asm volatile("s_waitcnt vmcnt(0)" ::: "memory");  // drain h stores
      if (tid == 0)
        __hip_atomic_store(gflags + j, t + 1, __ATOMIC_RELAXED, __HIP_MEMORY_SCOPE_AGENT);
      if (tid < 64) {
        int tgt = t + 1;
        while (true) {
          int v = __hip_atomic_load(gflags + tid, __ATOMIC_RELAXED, __HIP_MEMORY_SCOPE_AGENT);
          if (__all(v >= tgt)) break;
          __builtin_amdgcn_s_sleep(1);
        }
      }
      __syncthreads();
    }
  }
}

// ---------------- raw_mean over T ----------------
__global__ void rawmean_kernel(const float* __restrict__ raw, float* __restrict__ out)
{
  int i = blockIdx.x * 256 + threadIdx.x;   // 65536
  int b = i >> 10, d = i & 1023;
  const float* r = raw + (size_t)b * Tv * Dv + d;
  float s = 0.f;
  for (int t = 0; t < Tv; ++t) s += r[(size_t)t * Dv];
  out[i] = s * (1.f / Tv);
}

// ---------------- gated fusion ----------------
__global__ __launch_bounds__(256) void gate1_kernel(
    const float* __restrict__ pooled, const float* __restrict__ rawmean,
    const float* __restrict__ w1, const float* __restrict__ b1, float* __restrict__ out)
{
  int b = blockIdx.x;
  __shared__ float cat[2048];
  for (int k = threadIdx.x; k < 1024; k += 256) {
    cat[k] = pooled[b * 1024 + k];
    cat[1024 + k] = rawmean[b * 1024 + k];
  }
  __syncthreads();
  for (int jj = 0; jj < 4; ++jj) {
    int j = threadIdx.x + jj * 256;
    float acc = b1[j];
    const float4* wr = (const float4*)(w1 + (size_t)j * 2048);
    for (int k4 = 0; k4 < 512; ++k4) {
      float4 w = wr[k4];
      acc += w.x * cat[k4 * 4] + w.y * cat[k4 * 4 + 1] + w.z * cat[k4 * 4 + 2] + w.w * cat[k4 * 4 + 3];
    }
    out[b * 1024 + j] = fmaxf(acc, 0.f);
  }
}

__global__ __launch_bounds__(256) void gate2_kernel(
    const float* __restrict__ gt1, const float* __restrict__ pooled,
    const float* __restrict__ rawmean,
    const float* __restrict__ w2, const float* __restrict__ b2, float* __restrict__ fused)
{
  int b = blockIdx.x;
  __shared__ float cl[1024];
  for (int k = threadIdx.x; k < 1024; k += 256) cl[k] = gt1[b * 1024 + k];
  __syncthreads();
  for (int jj = 0; jj < 4; ++jj) {
    int j = threadIdx.x + jj * 256;
    float acc = b2[j];
    const float4* wr = (const float4*)(w2 + (size_t)j * 1024);
    for (int k4 = 0; k4 < 256; ++k4) {
      float4 w = wr[k4];
      acc += w.x * cl[k4 * 4] + w.y * cl[k4 * 4 + 1] + w.z * cl[k4 * 4 + 2] + w.w * cl[k4 * 4 + 3];
    }
    float gv = sigmoidf_(acc);
    int idx = b * 1024 + j;
    fused[idx] = gv * pooled[idx] + (1.f - gv) * rawmean[idx];
  }
}

// ---------------- stage head ----------------
__global__ __launch_bounds__(128) void head_kernel(
    const float* __restrict__ fused,
    const float* __restrict__ w1, const float* __restrict__ b1,
    const float* __restrict__ gam, const float* __restrict__ bet,
    const float* __restrict__ w2, const float* __restrict__ b2,
    float* __restrict__ logits)
{
  int b = blockIdx.x;
  __shared__ float fl[1024];
  __shared__ float h1[512];
  __shared__ float rs[4];
  for (int k = threadIdx.x; k < 1024; k += 128) fl[k] = fused[b * 1024 + k];
  __syncthreads();
  float vals[4]; float s = 0.f, s2 = 0.f;
  for (int jj = 0; jj < 4; ++jj) {
    int j = threadIdx.x + jj * 128;
    float acc = b1[j];
    const float4* wr = (const float4*)(w1 + (size_t)j * 1024);
    for (int k4 = 0; k4 < 256; ++k4) {
      float4 w = wr[k4];
      acc += w.x * fl[k4 * 4] + w.y * fl[k4 * 4 + 1] + w.z * fl[k4 * 4 + 2] + w.w * fl[k4 * 4 + 3];
    }
    vals[jj] = acc; s += acc; s2 += acc * acc;
  }
  for (int off = 32; off; off >>= 1) { s += __shfl_down(s, off); s2 += __shfl_down(s2, off); }
  int wid = threadIdx.x >> 6;
  if ((threadIdx.x & 63) == 0) { rs[wid] = s; rs[2 + wid] = s2; }
  __syncthreads();
  s = rs[0] + rs[1]; s2 = rs[2] + rs[3];
  float mu = s / 512.f, var = s2 / 512.f - mu * mu;
  float rstd = rsqrtf(var + 1e-5f);
  for (int jj = 0; jj < 4; ++jj) {
    int j = threadIdx.x + jj * 128;
    h1[j] = fmaxf((vals[jj] - mu) * rstd * gam[j] + bet[j], 0.f);
  }
  __syncthreads();
  if (threadIdx.x < 5) {
    float acc = b2[threadIdx.x];
    for (int k = 0; k < 512; ++k) acc += h1[k] * w2[threadIdx.x * 512 + k];
    logits[b * 5 + threadIdx.x] = acc;
  }
}

// ---------------- memory bank update ----------------
__global__ void scatter_last_kernel(const int* __restrict__ cls,
                                    const int* __restrict__ stage, int* __restrict__ last)
{
  int i = blockIdx.x * 256 + threadIdx.x;
  if (i < NT) {
    int b = i >> 7;
    int p = cls[b] * NS + stage[i];
    atomicMax(&last[p], i);
  }
}

__global__ __launch_bounds__(256) void mem_update_kernel(
    const float* __restrict__ mem_in, const float* __restrict__ raw,
    const int* __restrict__ cnt_in, const int* __restrict__ last,
    float* __restrict__ mem_out, float* __restrict__ cnt_out)
{
  int p = blockIdx.x;
  int cnt = cnt_in[p];
  int li = last[p];
  bool present = li >= 0;
  bool full = cnt >= NM;
  int wp = full ? NM - 1 : cnt;
  const float* newf = raw + (size_t)(li < 0 ? 0 : li) * Dv;
  const float* src = mem_in + (size_t)p * NM * Dv;
  float* dst = mem_out + (size_t)p * NM * Dv;
  for (int idx = threadIdx.x; idx < NM * Dv / 4; idx += 256) {
    int m = idx >> 8;          // 256 float4 per row
    int dq = idx & 255;
    float4 v;
    if (present && full) {
      v = (m < NM - 1) ? *(const float4*)(src + (size_t)(m + 1) * Dv + dq * 4)
                       : *(const float4*)(newf + dq * 4);
    } else if (present) {
      v = (m == wp) ? *(const float4*)(newf + dq * 4)
                    : *(const float4*)(src + (size_t)m * Dv + dq * 4);
    } else {
      v = *(const float4*)(src + (size_t)m * Dv + dq * 4);
    }
    *(float4*)(dst + (size_t)m * Dv + dq * 4) = v;
  }
  if (threadIdx.x == 0)
    cnt_out[p] = (float)(cnt + ((present && !full) ? 1 : 0));
}

// =======================================================================
extern "C" void kernel_launch(void* const* d_in, const int* in_sizes, int n_in,
                              void* d_out, int out_size, void* d_ws, size_t ws_size,
                              hipStream_t stream)
{
  (void)in_sizes; (void)n_in; (void)out_size; (void)ws_size;
  const float* x       = (const float*)d_in[0];
  const int* stage     = (const int*)d_in[1];
  const int* cls       = (const int*)d_in[2];
  const float* enc_w1  = (const float*)d_in[3];
  const float* enc_b1  = (const float*)d_in[4];
  const float* enc_g1  = (const float*)d_in[5];
  const float* enc_bb1 = (const float*)d_in[6];
  const float* enc_w2  = (const float*)d_in[7];
  const float* enc_b2  = (const float*)d_in[8];
  const float* enc_g2  = (const float*)d_in[9];
  const float* enc_bb2 = (const float*)d_in[10];
  const float* qkv_w   = (const float*)d_in[11];
  const float* qkv_b   = (const float*)d_in[12];
  const float* out_w   = (const float*)d_in[13];
  const float* out_b   = (const float*)d_in[14];
  const float* norm_g  = (const float*)d_in[15];
  const float* norm_b  = (const float*)d_in[16];
  const float* Wih0    = (const float*)d_in[17];
  const float* Whh0    = (const float*)d_in[18];
  const float* bih0    = (const float*)d_in[19];
  const float* bhh0    = (const float*)d_in[20];
  const float* Wih1    = (const float*)d_in[21];
  const float* Whh1    = (const float*)d_in[22];
  const float* bih1    = (const float*)d_in[23];
  const float* bhh1    = (const float*)d_in[24];
  const float* head_w1 = (const float*)d_in[25];
  const float* head_b1 = (const float*)d_in[26];
  const float* head_g  = (const float*)d_in[27];
  const float* head_bb = (const float*)d_in[28];
  const float* head_w2 = (const float*)d_in[29];
  const float* head_b2 = (const float*)d_in[30];
  const float* gate_w1 = (const float*)d_in[31];
  const float* gate_b1 = (const float*)d_in[32];
  const float* gate_w2 = (const float*)d_in[33];
  const float* gate_b2 = (const float*)d_in[34];
  const float* mem_in  = (const float*)d_in[35];
  const int* cnt_in    = (const int*)d_in[36];

  float* out = (float*)d_out;
  float* out_fused  = out;                      // 65536
  float* out_raw    = out + 65536;              // 8388608
  float* out_logits = out + 8454144;            // 320
  float* out_mem    = out + 8454464;            // 51200000
  float* out_cnt    = out + 59654464;           // 5000

  // ---- workspace layout (bf16 weights + small state), ~41 MB ----
  char* wsb = (char*)d_ws;
  auto alloc = [&](size_t bytes) { char* p = wsb; wsb += (bytes + 255) & ~(size_t)255; return p; };
  bf16* wq16   = (bf16*)alloc((size_t)3072 * 1024 * 2);
  bf16* wo16   = (bf16*)alloc((size_t)1024 * 1024 * 2);
  bf16* wih0b  = (bf16*)alloc((size_t)4096 * 1024 * 2);
  bf16* whh0b  = (bf16*)alloc((size_t)4096 * 1024 * 2);
  bf16* wih1b  = (bf16*)alloc((size_t)4096 * 1024 * 2);
  bf16* whh1b  = (bf16*)alloc((size_t)4096 * 1024 * 2);
  float* bsum0 = (float*)alloc(4096 * 4);
  float* bsum1 = (float*)alloc(4096 * 4);
  bf16* hbuf   = (bf16*)alloc((size_t)4 * 2 * 16384 * 2);  // 4 groups x 2 x 16K bf16
  float* pooled  = (float*)alloc(65536 * 4);
  float* rawmean = (float*)alloc(65536 * 4);
  float* gt1     = (float*)alloc(65536 * 4);
  int* last      = (int*)alloc(5000 * 4);
  int* flags     = (int*)alloc(2048);            // 2 layers x 256 ints

  // ---- large activation scratch inside the new_mem output slot (204.8 MB),
  //      all uses finish before mem_update overwrites it ----
  char* orb = (char*)out_mem;
  bf16* qkv16 = (bf16*)(orb + 0);            // 50,331,648 B
  bf16* y016  = (bf16*)(orb + 50331648);     // 16,777,216 B
  bf16* xgT   = (bf16*)(orb + 67108864);     // 67,108,864 B  [t][b][4096]
  bf16* xpe16 = (bf16*)(orb + 134217728);    // 16,777,216 B
  bf16* o16   = (bf16*)(orb + 150994944);    // 16,777,216 B
  bf16* ao16  = (bf16*)(orb + 167772160);    // 16,777,216 B
  bf16* raw16 = (bf16*)(orb + 184549376);    // 16,777,216 B (ends 201,326,592)
  float* embf = (float*)(orb + 201326592);   //  2,621,440 B (ends 203,948,032)

  // 1) weight conversions + bias sums
  f2b_kernel<<<3072, 256, 0, stream>>>(qkv_w, wq16, 786432);
  f2b_kernel<<<1024, 256, 0, stream>>>(out_w, wo16, 262144);
  f2b_kernel<<<4096, 256, 0, stream>>>(Wih0, wih0b, 1048576);
  f2b_kernel<<<4096, 256, 0, stream>>>(Whh0, whh0b, 1048576);
  f2b_kernel<<<4096, 256, 0, stream>>>(Wih1, wih1b, 1048576);
  f2b_kernel<<<4096, 256, 0, stream>>>(Whh1, whh1b, 1048576);
  add2_kernel<<<16, 256, 0, stream>>>(bih0, bhh0, bsum0, 4096);
  add2_kernel<<<16, 256, 0, stream>>>(bih1, bhh1, bsum1, 4096);

  // 2) encoder: 640-row emb table, then fused add -> xpe16
  emb_kernel<<<Tv * NS, 128, 0, stream>>>(enc_w1, enc_b1, enc_g1, enc_bb1,
                                          enc_w2, enc_b2, enc_g2, enc_bb2, embf);
  addemb_kernel<<<NT, 256, 0, stream>>>(x, stage, embf, xpe16);

  // 3) qkv = xpe @ qkv_w^T + b
  gemm128<<<dim3(NT / 128, 3072 / 128), 256, 0, stream>>>(xpe16, wq16, qkv_b, qkv16,
                                                          NT, 3072, Dv, 0);

  // 4) attention -> o16
  attn_kernel<<<Bv * Hv, 256, 0, stream>>>(qkv16, o16);

  // 5) out projection -> ao16
  gemm128<<<dim3(NT / 128, 1024 / 128), 256, 0, stream>>>(o16, wo16, out_b, ao16,
                                                          NT, Dv, Dv, 0);

  // 6) residual + LN -> raw (d_out) + raw16
  residual_ln_kernel<<<NT, 256, 0, stream>>>(xpe16, ao16, norm_g, norm_b, out_raw, raw16);

  // 7) LSTM layer 0: input gates (time-major), then persistent recurrence
  gemm128<<<dim3(NT / 128, 4096 / 128), 256, 0, stream>>>(raw16, wih0b, bsum0, xgT,
                                                          NT, 4096, Dv, 1);
  hipMemsetAsync(flags, 0, 2048, stream);
  lstm_seq<<<256, 256, 0, stream>>>(whh0b, xgT, hbuf, y016, nullptr, flags);

  // 8) LSTM layer 1
  gemm128<<<dim3(NT / 128, 4096 / 128), 256, 0, stream>>>(y016, wih1b, bsum1, xgT,
                                                          NT, 4096, Dv, 1);
  lstm_seq<<<256, 256, 0, stream>>>(whh1b, xgT, hbuf, nullptr, pooled, flags + 256);

  // 9) raw_mean, gated fusion, head
  rawmean_kernel<<<256, 256, 0, stream>>>(out_raw, rawmean);
  gate1_kernel<<<Bv, 256, 0, stream>>>(pooled, rawmean, gate_w1, gate_b1, gt1);
  gate2_kernel<<<Bv, 256, 0, stream>>>(gt1, pooled, rawmean, gate_w2, gate_b2, out_fused);
  head_kernel<<<Bv, 128, 0, stream>>>(out_fused, head_w1, head_b1, head_g, head_bb,
                                      head_w2, head_b2, out_logits);

  // 10) memory bank update (overwrites the scratch region last)
  hipMemsetAsync(last, 0xFF, 5000 * 4, stream);
  scatter_last_kernel<<<32, 256, 0, stream>>>(cls, stage, last);
  mem_update_kernel<<<NC * NS, 256, 0, stream>>>(mem_in, out_raw, cnt_in, last, out_mem, out_cnt);
}

// Round 6
// 3035.226 us; speedup vs baseline: 2.8372x; 1.1431x over previous
//
#include <hip/hip_runtime.h>
#include <hip/hip_bf16.h>

typedef __bf16 bf16x8 __attribute__((ext_vector_type(8)));
typedef float  f32x4  __attribute__((ext_vector_type(4)));
typedef unsigned long long u64;
using bf16 = __hip_bfloat16;

constexpr int Bv = 64, Tv = 128, Dv = 1024, Hv = 8, HDv = 128;
constexpr int NC = 1000, NS = 5, NM = 10;
constexpr int NT = Bv * Tv;           // 8192 tokens

static __device__ __forceinline__ float sigmoidf_(float x) {
  return 1.f / (1.f + __expf(-x));
}

static __device__ __forceinline__ void gload_lds16(const bf16* g, bf16* l) {
  __builtin_amdgcn_global_load_lds(
      (const __attribute__((address_space(1))) void*)g,
      (__attribute__((address_space(3))) void*)l, 16, 0, 0);
}

// ---------------- m97-structure GEMM: C[M,N] = A[M,K] @ W[N,K]^T + bias -------
// 128x128 tile, BK=32, 4 waves (2x2 of 64x64), global_load_lds(16B) staging.
// transT: write C row token=b*T+t at output row t*64+b (time-major for LSTM).
__global__ __launch_bounds__(256) void gemm128(
    const bf16* __restrict__ A, const bf16* __restrict__ W,
    const float* __restrict__ bias, bf16* __restrict__ C,
    int M, int N, int K, int transT)
{
  __shared__ bf16 sa[128 * 32];
  __shared__ bf16 sb[128 * 32];
  int wave = threadIdx.x >> 6, lane = threadIdx.x & 63;
  int l15 = lane & 15, lhi = lane >> 4;
  int wr = wave >> 1, wc = wave & 1;
  int row0 = blockIdx.x * 128, col0 = blockIdx.y * 128;
  f32x4 acc[4][4];
#pragma unroll
  for (int m = 0; m < 4; ++m)
#pragma unroll
    for (int n = 0; n < 4; ++n) acc[m][n] = f32x4{0.f, 0.f, 0.f, 0.f};

  int sr = wave * 32 + (lane >> 2);
  int sk = (lane & 3) * 8;
  const bf16* srcA = A + (size_t)(row0 + sr) * K + sk;
  const bf16* srcB = W + (size_t)(col0 + sr) * K + sk;
  bf16* dstA0 = &sa[wave * 1024];
  bf16* dstB0 = &sb[wave * 1024];

  for (int k0 = 0; k0 < K; k0 += 32) {
    __syncthreads();
    gload_lds16(srcA + k0,            dstA0);
    gload_lds16(srcA + 16 * K + k0,   dstA0 + 512);
    gload_lds16(srcB + k0,            dstB0);
    gload_lds16(srcB + 16 * K + k0,   dstB0 + 512);
    __syncthreads();
    bf16x8 af[4], bfr[4];
#pragma unroll
    for (int m = 0; m < 4; ++m)
      af[m] = *reinterpret_cast<const bf16x8*>(&sa[(wr * 64 + m * 16 + l15) * 32 + lhi * 8]);
#pragma unroll
    for (int n = 0; n < 4; ++n)
      bfr[n] = *reinterpret_cast<const bf16x8*>(&sb[(wc * 64 + n * 16 + l15) * 32 + lhi * 8]);
#pragma unroll
    for (int m = 0; m < 4; ++m)
#pragma unroll
      for (int n = 0; n < 4; ++n)
        acc[m][n] = __builtin_amdgcn_mfma_f32_16x16x32_bf16(af[m], bfr[n], acc[m][n], 0, 0, 0);
  }

#pragma unroll
  for (int n = 0; n < 4; ++n) {
    int col = col0 + wc * 64 + n * 16 + l15;
    float bv = bias ? bias[col] : 0.f;
#pragma unroll
    for (int m = 0; m < 4; ++m) {
#pragma unroll
      for (int r = 0; r < 4; ++r) {
        int row = row0 + wr * 64 + m * 16 + lhi * 4 + r;
        int orow = transT ? ((row & (Tv - 1)) * Bv + (row >> 7)) : row;
        C[(size_t)orow * N + col] = __float2bfloat16(acc[m][n][r] + bv);
      }
    }
  }
}

// ---------------- f32 -> bf16 convert ----------------
__global__ void f2b_kernel(const float* __restrict__ s, bf16* __restrict__ d, int n4)
{
  int i = blockIdx.x * 256 + threadIdx.x;
  if (i < n4) {
    float4 v = ((const float4*)s)[i];
    bf16* o = d + (size_t)i * 4;
    o[0] = __float2bfloat16(v.x); o[1] = __float2bfloat16(v.y);
    o[2] = __float2bfloat16(v.z); o[3] = __float2bfloat16(v.w);
  }
}

__global__ void add2_kernel(const float* __restrict__ a, const float* __restrict__ b,
                            float* __restrict__ o, int n)
{
  int i = blockIdx.x * 256 + threadIdx.x;
  if (i < n) o[i] = a[i] + b[i];
}

// ---------------- emb table: 640 distinct (t, stage) rows ----------------
__global__ __launch_bounds__(128) void emb_kernel(
    const float* __restrict__ w1, const float* __restrict__ b1,
    const float* __restrict__ g1, const float* __restrict__ bb1,
    const float* __restrict__ w2, const float* __restrict__ b2,
    const float* __restrict__ g2, const float* __restrict__ bb2,
    float* __restrict__ emb)
{
  int combo = blockIdx.x;                 // t*5 + s
  float tpos = (float)(combo / 5);
  float stg  = (float)(combo % 5);
  int tid = threadIdx.x;
  __shared__ float hb[64];
  __shared__ float rs[4];
  if (tid < 64) {
    float v = w1[tid * 2] * tpos + w1[tid * 2 + 1] * stg + b1[tid];
    float s = v, s2 = v * v;
    for (int off = 32; off; off >>= 1) { s += __shfl_down(s, off); s2 += __shfl_down(s2, off); }
    s = __shfl(s, 0); s2 = __shfl(s2, 0);
    float mu = s / 64.f, var = s2 / 64.f - mu * mu;
    float h = (v - mu) * rsqrtf(var + 1e-5f) * g1[tid] + bb1[tid];
    hb[tid] = fmaxf(h, 0.f);
  }
  __syncthreads();
  float outv[8];
  float s = 0.f, s2 = 0.f;
  int d0 = tid * 8;
#pragma unroll
  for (int o = 0; o < 8; ++o) {
    int d = d0 + o;
    float acc = b2[d];
    const float4* wr = (const float4*)(w2 + (size_t)d * 64);
#pragma unroll
    for (int k4 = 0; k4 < 16; ++k4) {
      float4 w = wr[k4];
      acc += w.x * hb[k4 * 4] + w.y * hb[k4 * 4 + 1] + w.z * hb[k4 * 4 + 2] + w.w * hb[k4 * 4 + 3];
    }
    outv[o] = acc; s += acc; s2 += acc * acc;
  }
  for (int off = 32; off; off >>= 1) { s += __shfl_down(s, off); s2 += __shfl_down(s2, off); }
  int wid = tid >> 6;
  if ((tid & 63) == 0) { rs[wid] = s; rs[2 + wid] = s2; }
  __syncthreads();
  s = rs[0] + rs[1]; s2 = rs[2] + rs[3];
  float mu = s / 1024.f, var = s2 / 1024.f - mu * mu;
  float rstd = rsqrtf(var + 1e-5f);
  float* op = emb + (size_t)combo * Dv + d0;
#pragma unroll
  for (int o = 0; o < 8; ++o) {
    int d = d0 + o;
    op[o] = (outv[o] - mu) * rstd * g2[d] + bb2[d];
  }
}

__global__ __launch_bounds__(256) void addemb_kernel(
    const float* __restrict__ x, const int* __restrict__ stage,
    const float* __restrict__ emb, bf16* __restrict__ xpe)
{
  int tok = blockIdx.x;
  int row = (tok & (Tv - 1)) * NS + stage[tok];
  const float4* xr = (const float4*)(x + (size_t)tok * Dv);
  const float4* er = (const float4*)(emb + (size_t)row * Dv);
  bf16* op = xpe + (size_t)tok * Dv + threadIdx.x * 4;
  float4 xv = xr[threadIdx.x], ev = er[threadIdx.x];
  op[0] = __float2bfloat16(xv.x + ev.x);
  op[1] = __float2bfloat16(xv.y + ev.y);
  op[2] = __float2bfloat16(xv.z + ev.z);
  op[3] = __float2bfloat16(xv.w + ev.w);
}

// ---------------- attention: per (b,h) flash-style, scalar fp32 ----------------
__global__ __launch_bounds__(256) void attn_kernel(const bf16* __restrict__ qkv,
                                                   bf16* __restrict__ o)
{
  __shared__ bf16 kl[128][128];
  __shared__ bf16 vl[128][128];
  int bh = blockIdx.x;
  int b = bh >> 3, h = bh & 7;
  int tid = threadIdx.x;
  int row = tid >> 1, hf = tid & 1;
  {
    const bf16* ks = qkv + (size_t)(b * Tv + row) * 3072 + Dv + h * HDv + hf * 64;
    const bf16* vs = ks + Dv;
    uint4* dk = (uint4*)&kl[row][hf * 64];
    uint4* dv = (uint4*)&vl[row][hf * 64];
    const uint4* sk = (const uint4*)ks;
    const uint4* sv = (const uint4*)vs;
#pragma unroll
    for (int i = 0; i < 8; ++i) { dk[i] = sk[i]; dv[i] = sv[i]; }
  }
  float qf[64];
  {
    const bf16* qs = qkv + (size_t)(b * Tv + row) * 3072 + h * HDv + hf * 64;
#pragma unroll
    for (int d2 = 0; d2 < 32; ++d2) {
      float2 f = __bfloat1622float2(*(const __hip_bfloat162*)(qs + 2 * d2));
      qf[2 * d2] = f.x; qf[2 * d2 + 1] = f.y;
    }
  }
  __syncthreads();
  float oacc[64];
#pragma unroll
  for (int d = 0; d < 64; ++d) oacc[d] = 0.f;
  float m = -1e30f, l = 0.f;
  const float scale = 0.088388347648318447f;  // 1/sqrt(128)
  for (int j = 0; j < 128; ++j) {
    float part = 0.f;
#pragma unroll
    for (int d2 = 0; d2 < 32; ++d2) {
      float2 kv2 = __bfloat1622float2(*(const __hip_bfloat162*)&kl[j][hf * 64 + 2 * d2]);
      part += qf[2 * d2] * kv2.x + qf[2 * d2 + 1] * kv2.y;
    }
    float sfull = (part + __shfl_xor(part, 1)) * scale;
    float mn = fmaxf(m, sfull);
    float al = __expf(m - mn);
    float p = __expf(sfull - mn);
    l = l * al + p;
#pragma unroll
    for (int d2 = 0; d2 < 32; ++d2) {
      float2 vv = __bfloat1622float2(*(const __hip_bfloat162*)&vl[j][hf * 64 + 2 * d2]);
      oacc[2 * d2]     = oacc[2 * d2] * al + p * vv.x;
      oacc[2 * d2 + 1] = oacc[2 * d2 + 1] * al + p * vv.y;
    }
    m = mn;
  }
  float rl = 1.f / l;
  bf16* od = o + (size_t)(b * Tv + row) * Dv + h * HDv + hf * 64;
#pragma unroll
  for (int d = 0; d < 64; ++d) od[d] = __float2bfloat16(oacc[d] * rl);
}

// ---------------- residual + LN -> raw (f32 to d_out) + raw16 -----------------
__global__ __launch_bounds__(256) void residual_ln_kernel(
    const bf16* __restrict__ xpe, const bf16* __restrict__ ao,
    const float* __restrict__ gam, const float* __restrict__ bet,
    float* __restrict__ rawf, bf16* __restrict__ raw16)
{
  int tok = blockIdx.x, tid = threadIdx.x;
  float v[4]; float s = 0.f, s2 = 0.f;
  __shared__ float rs[8];
#pragma unroll
  for (int q = 0; q < 4; ++q) {
    int d = tid + q * 256;
    size_t idx = (size_t)tok * Dv + d;
    float a = __bfloat162float(xpe[idx]) + __bfloat162float(ao[idx]);
    v[q] = a; s += a; s2 += a * a;
  }
  for (int off = 32; off; off >>= 1) { s += __shfl_down(s, off); s2 += __shfl_down(s2, off); }
  int wid = tid >> 6;
  if ((tid & 63) == 0) { rs[wid] = s; rs[4 + wid] = s2; }
  __syncthreads();
  s = rs[0] + rs[1] + rs[2] + rs[3];
  s2 = rs[4] + rs[5] + rs[6] + rs[7];
  float mu = s / 1024.f, var = s2 / 1024.f - mu * mu;
  float rstd = rsqrtf(var + 1e-5f);
#pragma unroll
  for (int q = 0; q < 4; ++q) {
    int d = tid + q * 256;
    size_t idx = (size_t)tok * Dv + d;
    float rv = (v[q] - mu) * rstd * gam[d] + bet[d];
    rawf[idx] = rv;
    raw16[idx] = __float2bfloat16(rv);
  }
}

// ---------------- fused 2-layer pipelined persistent LSTM ---------------------
// Grid 256 x 256. Block (gid,j): batches gid*16..+15, units j*16..+15, both
// layers. Super-step s (0..128): layer0 computes t=s, layer1 computes t=s-1.
// h0(t)==y0(t): staged ONCE into LDS, consumed by L0 (Whh0, regs) and L1
// (Wih1, regs). h1 staged into upper LDS cols, Whh1 frags streamed from L2.
// h0buf/h1buf: [parity][group][j][64 u64] -> stride 4096 u64 per (parity,group).
// Flag barrier per super-step: flag[b] = completed super-steps; wait all>=s.
__global__ __launch_bounds__(256, 1) void lstm_fused(
    const bf16* __restrict__ Whh0, const bf16* __restrict__ Wih1,
    const bf16* __restrict__ Whh1, const bf16* __restrict__ xgT,
    const float* __restrict__ bsum1,
    bf16* h0buf, bf16* h1buf,          // each [2][4][4096 u64]
    float* __restrict__ pooled, int* flags)   // flags[4][64] pre-zeroed
{
  const int bid = blockIdx.x;
  const int xcd = bid & 7, idx = bid >> 3;
  const int j   = xcd * 8 + (idx & 7);   // unit block 0..63
  const int gid = idx >> 3;              // batch group 0..3
  const int u0  = j * 16;
  const int tid = threadIdx.x;
  const int g = tid >> 6, lane = tid & 63;
  const int l15 = lane & 15, lhi = lane >> 4;

  // preload weights: Whh0 + Wih1 rows for (gate g, units u0..u0+15)
  bf16x8 w0[32], w1[32];
  {
    const bf16* r0 = Whh0 + (size_t)(g * Dv + u0 + l15) * Dv;
    const bf16* r1 = Wih1 + (size_t)(g * Dv + u0 + l15) * Dv;
#pragma unroll
    for (int i = 0; i < 32; ++i) {
      w0[i] = *reinterpret_cast<const bf16x8*>(r0 + i * 32 + lhi * 8);
      w1[i] = *reinterpret_cast<const bf16x8*>(r1 + i * 32 + lhi * 8);
    }
  }
  const bf16* rh1 = Whh1 + (size_t)(g * Dv + u0 + l15) * Dv;
  const float bs1 = bsum1[g * Dv + u0 + l15];

  __shared__ bf16 hA[16 * 2056];       // rows=batch, cols 0..1023 h0/y0, 1024..2047 h1, +8 pad
  __shared__ float gl[4][16][16];
  __shared__ bf16 hstage[256];

  float c0 = 0.f, c1 = 0.f;
  const int bb_t = tid >> 4, uu_t = tid & 15;
  int* gflags = flags + gid * 64;
  const int koff = lhi * 8;

  for (int s = 0; s <= Tv; ++s) {
    // ---- xg prefetch for layer0 step s (independent of barrier) ----
    float xv[4];
    if (s < Tv) {
      const bf16* xg_t = xgT + (size_t)s * (Bv * 4 * Dv) + (size_t)(gid * 16) * (4 * Dv)
                         + g * Dv + u0 + l15;
#pragma unroll
      for (int r = 0; r < 4; ++r)
        xv[r] = __bfloat162float(xg_t[(size_t)(lhi * 4 + r) * (4 * Dv)]);
    }
    // ---- barrier: all group flags >= s ----
    if (s > 0) {
      if (tid < 64) {
        while (true) {
          int v = __hip_atomic_load(gflags + tid, __ATOMIC_RELAXED, __HIP_MEMORY_SCOPE_AGENT);
          if (__all(v >= s)) break;
          __builtin_amdgcn_s_sleep(1);
        }
      }
      __syncthreads();                                   // S1
      // ---- stage h0(s-1) -> cols 0..1023 ----
      {
        const u64* src = (const u64*)h0buf + (size_t)(((s - 1) & 1) * 4 + gid) * 4096;
        u64* dst = (u64*)hA;
#pragma unroll
        for (int it = 0; it < 16; ++it) {
          int id = it * 256 + tid;                       // 4096 u64
          int jc = id >> 6, r = id & 63;
          int bb = r >> 2, uq = r & 3;
          u64 v = __hip_atomic_load(src + id, __ATOMIC_RELAXED, __HIP_MEMORY_SCOPE_AGENT);
          dst[bb * 514 + jc * 4 + uq] = v;
        }
      }
      // ---- stage h1(s-2) -> cols 1024..2047 ----
      if (s >= 2) {
        const u64* src = (const u64*)h1buf + (size_t)(((s - 2) & 1) * 4 + gid) * 4096;
        u64* dst = (u64*)hA + 256;
#pragma unroll
        for (int it = 0; it < 16; ++it) {
          int id = it * 256 + tid;
          int jc = id >> 6, r = id & 63;
          int bb = r >> 2, uq = r & 3;
          u64 v = __hip_atomic_load(src + id, __ATOMIC_RELAXED, __HIP_MEMORY_SCOPE_AGENT);
          dst[bb * 514 + jc * 4 + uq] = v;
        }
      }
      __syncthreads();                                   // S2
    }

    // ================= layer 0: t = s =================
    if (s < Tv) {
      f32x4 aA = f32x4{0.f, 0.f, 0.f, 0.f}, aB = aA;
      if (s > 0) {
#pragma unroll
        for (int k0 = 0; k0 < 32; k0 += 2) {
          bf16x8 a0 = *reinterpret_cast<const bf16x8*>(&hA[l15 * 2056 + k0 * 32 + koff]);
          bf16x8 a1 = *reinterpret_cast<const bf16x8*>(&hA[l15 * 2056 + (k0 + 1) * 32 + koff]);
          aA = __builtin_amdgcn_mfma_f32_16x16x32_bf16(a0, w0[k0], aA, 0, 0, 0);
          aB = __builtin_amdgcn_mfma_f32_16x16x32_bf16(a1, w0[k0 + 1], aB, 0, 0, 0);
        }
      }
#pragma unroll
      for (int r = 0; r < 4; ++r)
        gl[g][lhi * 4 + r][l15] = aA[r] + aB[r] + xv[r];
      __syncthreads();                                   // S3
      {
        float gi = gl[0][bb_t][uu_t], gf = gl[1][bb_t][uu_t];
        float gc = gl[2][bb_t][uu_t], go = gl[3][bb_t][uu_t];
        float cn = sigmoidf_(gf) * c0 + sigmoidf_(gi) * tanhf(gc);
        float hn = sigmoidf_(go) * tanhf(cn);
        c0 = cn;
        hstage[bb_t * 16 + uu_t] = __float2bfloat16(hn);
      }
      __syncthreads();                                   // S4
      if (tid < 64) {
        u64* dst = (u64*)h0buf + (size_t)((s & 1) * 4 + gid) * 4096 + j * 64 + tid;
        __hip_atomic_store(dst, ((u64*)hstage)[tid], __ATOMIC_RELAXED, __HIP_MEMORY_SCOPE_AGENT);
      }
    }

    // ================= layer 1: t = s-1 =================
    if (s > 0) {
      f32x4 aA = f32x4{0.f, 0.f, 0.f, 0.f}, aB = aA;
#pragma unroll
      for (int k0 = 0; k0 < 32; k0 += 2) {               // y0 part (regs Wih1)
        bf16x8 a0 = *reinterpret_cast<const bf16x8*>(&hA[l15 * 2056 + k0 * 32 + koff]);
        bf16x8 a1 = *reinterpret_cast<const bf16x8*>(&hA[l15 * 2056 + (k0 + 1) * 32 + koff]);
        aA = __builtin_amdgcn_mfma_f32_16x16x32_bf16(a0, w1[k0], aA, 0, 0, 0);
        aB = __builtin_amdgcn_mfma_f32_16x16x32_bf16(a1, w1[k0 + 1], aB, 0, 0, 0);
      }
      if (s >= 2) {
#pragma unroll
        for (int k0 = 0; k0 < 32; k0 += 2) {             // h1 part (Whh1 from L2)
          bf16x8 b0 = *reinterpret_cast<const bf16x8*>(rh1 + k0 * 32 + koff);
          bf16x8 b1 = *reinterpret_cast<const bf16x8*>(rh1 + (k0 + 1) * 32 + koff);
          bf16x8 a0 = *reinterpret_cast<const bf16x8*>(&hA[l15 * 2056 + 1024 + k0 * 32 + koff]);
          bf16x8 a1 = *reinterpret_cast<const bf16x8*>(&hA[l15 * 2056 + 1024 + (k0 + 1) * 32 + koff]);
          aA = __builtin_amdgcn_mfma_f32_16x16x32_bf16(a0, b0, aA, 0, 0, 0);
          aB = __builtin_amdgcn_mfma_f32_16x16x32_bf16(a1, b1, aB, 0, 0, 0);
        }
      }
#pragma unroll
      for (int r = 0; r < 4; ++r)
        gl[g][lhi * 4 + r][l15] = aA[r] + aB[r] + bs1;
      __syncthreads();                                   // S5
      {
        float gi = gl[0][bb_t][uu_t], gf = gl[1][bb_t][uu_t];
        float gc = gl[2][bb_t][uu_t], go = gl[3][bb_t][uu_t];
        float cn = sigmoidf_(gf) * c1 + sigmoidf_(gi) * tanhf(gc);
        float hn = sigmoidf_(go) * tanhf(cn);
        c1 = cn;
        hstage[bb_t * 16 + uu_t] = __float2bfloat16(hn);
        if (s == Tv) pooled[(gid * 16 + bb_t) * Dv + u0 + uu_t] = hn;
      }
      __syncthreads();                                   // S6
      if (tid >= 64 && tid < 128) {
        int q = tid - 64;
        u64* dst = (u64*)h1buf + (size_t)(((s - 1) & 1) * 4 + gid) * 4096 + j * 64 + q;
        __hip_atomic_store(dst, ((u64*)hstage)[q], __ATOMIC_RELAXED, __HIP_MEMORY_SCOPE_AGENT);
      }
    }

    // ---- drain + flag ----
    if (s < Tv) {
      asm volatile("s_waitcnt vmcnt(0)" ::: "memory");
      __syncthreads();                                   // S7
      if (tid == 0)
        __hip_atomic_store(gflags + j, s + 1, __ATOMIC_RELAXED, __HIP_MEMORY_SCOPE_AGENT);
    }
  }
}

// ---------------- raw_mean over T ----------------
__global__ void rawmean_kernel(const float* __restrict__ raw, float* __restrict__ out)
{
  int i = blockIdx.x * 256 + threadIdx.x;   // 65536
  int b = i >> 10, d = i & 1023;
  const float* r = raw + (size_t)b * Tv * Dv + d;
  float s = 0.f;
  for (int t = 0; t < Tv; ++t) s += r[(size_t)t * Dv];
  out[i] = s * (1.f / Tv);
}

// ---------------- gated fusion ----------------
__global__ __launch_bounds__(256) void gate1_kernel(
    const float* __restrict__ pooled, const float* __restrict__ rawmean,
    const float* __restrict__ w1, const float* __restrict__ b1, float* __restrict__ out)
{
  int b = blockIdx.x;
  __shared__ float cat[2048];
  for (int k = threadIdx.x; k < 1024; k += 256) {
    cat[k] = pooled[b * 1024 + k];
    cat[1024 + k] = rawmean[b * 1024 + k];
  }
  __syncthreads();
  for (int jj = 0; jj < 4; ++jj) {
    int j = threadIdx.x + jj * 256;
    float acc = b1[j];
    const float4* wr = (const float4*)(w1 + (size_t)j * 2048);
    for (int k4 = 0; k4 < 512; ++k4) {
      float4 w = wr[k4];
      acc += w.x * cat[k4 * 4] + w.y * cat[k4 * 4 + 1] + w.z * cat[k4 * 4 + 2] + w.w * cat[k4 * 4 + 3];
    }
    out[b * 1024 + j] = fmaxf(acc, 0.f);
  }
}

__global__ __launch_bounds__(256) void gate2_kernel(
    const float* __restrict__ gt1, const float* __restrict__ pooled,
    const float* __restrict__ rawmean,
    const float* __restrict__ w2, const float* __restrict__ b2, float* __restrict__ fused)
{
  int b = blockIdx.x;
  __shared__ float cl[1024];
  for (int k = threadIdx.x; k < 1024; k += 256) cl[k] = gt1[b * 1024 + k];
  __syncthreads();
  for (int jj = 0; jj < 4; ++jj) {
    int j = threadIdx.x + jj * 256;
    float acc = b2[j];
    const float4* wr = (const float4*)(w2 + (size_t)j * 1024);
    for (int k4 = 0; k4 < 256; ++k4) {
      float4 w = wr[k4];
      acc += w.x * cl[k4 * 4] + w.y * cl[k4 * 4 + 1] + w.z * cl[k4 * 4 + 2] + w.w * cl[k4 * 4 + 3];
    }
    float gv = sigmoidf_(acc);
    int idx = b * 1024 + j;
    fused[idx] = gv * pooled[idx] + (1.f - gv) * rawmean[idx];
  }
}

// ---------------- stage head ----------------
__global__ __launch_bounds__(128) void head_kernel(
    const float* __restrict__ fused,
    const float* __restrict__ w1, const float* __restrict__ b1,
    const float* __restrict__ gam, const float* __restrict__ bet,
    const float* __restrict__ w2, const float* __restrict__ b2,
    float* __restrict__ logits)
{
  int b = blockIdx.x;
  __shared__ float fl[1024];
  __shared__ float h1[512];
  __shared__ float rs[4];
  for (int k = threadIdx.x; k < 1024; k += 128) fl[k] = fused[b * 1024 + k];
  __syncthreads();
  float vals[4]; float s = 0.f, s2 = 0.f;
  for (int jj = 0; jj < 4; ++jj) {
    int j = threadIdx.x + jj * 128;
    float acc = b1[j];
    const float4* wr = (const float4*)(w1 + (size_t)j * 1024);
    for (int k4 = 0; k4 < 256; ++k4) {
      float4 w = wr[k4];
      acc += w.x * fl[k4 * 4] + w.y * fl[k4 * 4 + 1] + w.z * fl[k4 * 4 + 2] + w.w * fl[k4 * 4 + 3];
    }
    vals[jj] = acc; s += acc; s2 += acc * acc;
  }
  for (int off = 32; off; off >>= 1) { s += __shfl_down(s, off); s2 += __shfl_down(s2, off); }
  int wid = threadIdx.x >> 6;
  if ((threadIdx.x & 63) == 0) { rs[wid] = s; rs[2 + wid] = s2; }
  __syncthreads();
  s = rs[0] + rs[1]; s2 = rs[2] + rs[3];
  float mu = s / 512.f, var = s2 / 512.f - mu * mu;
  float rstd = rsqrtf(var + 1e-5f);
  for (int jj = 0; jj < 4; ++jj) {
    int j = threadIdx.x + jj * 128;
    h1[j] = fmaxf((vals[jj] - mu) * rstd * gam[j] + bet[j], 0.f);
  }
  __syncthreads();
  if (threadIdx.x < 5) {
    float acc = b2[threadIdx.x];
    for (int k = 0; k < 512; ++k) acc += h1[k] * w2[threadIdx.x * 512 + k];
    logits[b * 5 + threadIdx.x] = acc;
  }
}

// ---------------- memory bank update ----------------
__global__ void scatter_last_kernel(const int* __restrict__ cls,
                                    const int* __restrict__ stage, int* __restrict__ last)
{
  int i = blockIdx.x * 256 + threadIdx.x;
  if (i < NT) {
    int b = i >> 7;
    int p = cls[b] * NS + stage[i];
    atomicMax(&last[p], i);
  }
}

__global__ __launch_bounds__(256) void mem_update_kernel(
    const float* __restrict__ mem_in, const float* __restrict__ raw,
    const int* __restrict__ cnt_in, const int* __restrict__ last,
    float* __restrict__ mem_out, float* __restrict__ cnt_out)
{
  int p = blockIdx.x;
  int cnt = cnt_in[p];
  int li = last[p];
  bool present = li >= 0;
  bool full = cnt >= NM;
  int wp = full ? NM - 1 : cnt;
  const float* newf = raw + (size_t)(li < 0 ? 0 : li) * Dv;
  const float* src = mem_in + (size_t)p * NM * Dv;
  float* dst = mem_out + (size_t)p * NM * Dv;
  for (int idx = threadIdx.x; idx < NM * Dv / 4; idx += 256) {
    int m = idx >> 8;          // 256 float4 per row
    int dq = idx & 255;
    float4 v;
    if (present && full) {
      v = (m < NM - 1) ? *(const float4*)(src + (size_t)(m + 1) * Dv + dq * 4)
                       : *(const float4*)(newf + dq * 4);
    } else if (present) {
      v = (m == wp) ? *(const float4*)(newf + dq * 4)
                    : *(const float4*)(src + (size_t)m * Dv + dq * 4);
    } else {
      v = *(const float4*)(src + (size_t)m * Dv + dq * 4);
    }
    *(float4*)(dst + (size_t)m * Dv + dq * 4) = v;
  }
  if (threadIdx.x == 0)
    cnt_out[p] = (float)(cnt + ((present && !full) ? 1 : 0));
}

// =======================================================================
extern "C" void kernel_launch(void* const* d_in, const int* in_sizes, int n_in,
                              void* d_out, int out_size, void* d_ws, size_t ws_size,
                              hipStream_t stream)
{
  (void)in_sizes; (void)n_in; (void)out_size; (void)ws_size;
  const float* x       = (const float*)d_in[0];
  const int* stage     = (const int*)d_in[1];
  const int* cls       = (const int*)d_in[2];
  const float* enc_w1  = (const float*)d_in[3];
  const float* enc_b1  = (const float*)d_in[4];
  const float* enc_g1  = (const float*)d_in[5];
  const float* enc_bb1 = (const float*)d_in[6];
  const float* enc_w2  = (const float*)d_in[7];
  const float* enc_b2  = (const float*)d_in[8];
  const float* enc_g2  = (const float*)d_in[9];
  const float* enc_bb2 = (const float*)d_in[10];
  const float* qkv_w   = (const float*)d_in[11];
  const float* qkv_b   = (const float*)d_in[12];
  const float* out_w   = (const float*)d_in[13];
  const float* out_b   = (const float*)d_in[14];
  const float* norm_g  = (const float*)d_in[15];
  const float* norm_b  = (const float*)d_in[16];
  const float* Wih0    = (const float*)d_in[17];
  const float* Whh0    = (const float*)d_in[18];
  const float* bih0    = (const float*)d_in[19];
  const float* bhh0    = (const float*)d_in[20];
  const float* Wih1    = (const float*)d_in[21];
  const float* Whh1    = (const float*)d_in[22];
  const float* bih1    = (const float*)d_in[23];
  const float* bhh1    = (const float*)d_in[24];
  const float* head_w1 = (const float*)d_in[25];
  const float* head_b1 = (const float*)d_in[26];
  const float* head_g  = (const float*)d_in[27];
  const float* head_bb = (const float*)d_in[28];
  const float* head_w2 = (const float*)d_in[29];
  const float* head_b2 = (const float*)d_in[30];
  const float* gate_w1 = (const float*)d_in[31];
  const float* gate_b1 = (const float*)d_in[32];
  const float* gate_w2 = (const float*)d_in[33];
  const float* gate_b2 = (const float*)d_in[34];
  const float* mem_in  = (const float*)d_in[35];
  const int* cnt_in    = (const int*)d_in[36];

  float* out = (float*)d_out;
  float* out_fused  = out;                      // 65536
  float* out_raw    = out + 65536;              // 8388608
  float* out_logits = out + 8454144;            // 320
  float* out_mem    = out + 8454464;            // 51200000
  float* out_cnt    = out + 59654464;           // 5000

  // ---- workspace layout (bf16 weights + small state), ~42 MB ----
  char* wsb = (char*)d_ws;
  auto alloc = [&](size_t bytes) { char* p = wsb; wsb += (bytes + 255) & ~(size_t)255; return p; };
  bf16* wq16   = (bf16*)alloc((size_t)3072 * 1024 * 2);
  bf16* wo16   = (bf16*)alloc((size_t)1024 * 1024 * 2);
  bf16* wih0b  = (bf16*)alloc((size_t)4096 * 1024 * 2);
  bf16* whh0b  = (bf16*)alloc((size_t)4096 * 1024 * 2);
  bf16* wih1b  = (bf16*)alloc((size_t)4096 * 1024 * 2);
  bf16* whh1b  = (bf16*)alloc((size_t)4096 * 1024 * 2);
  float* bsum0 = (float*)alloc(4096 * 4);
  float* bsum1 = (float*)alloc(4096 * 4);
  bf16* h0buf  = (bf16*)alloc((size_t)2 * 4 * 16384 * 2);  // [parity][group]: 4096 u64 each
  bf16* h1buf  = (bf16*)alloc((size_t)2 * 4 * 16384 * 2);
  float* pooled  = (float*)alloc(65536 * 4);
  float* rawmean = (float*)alloc(65536 * 4);
  float* gt1     = (float*)alloc(65536 * 4);
  int* last      = (int*)alloc(5000 * 4);
  int* flags     = (int*)alloc(1024);            // 4 groups x 64 ints

  // ---- large activation scratch inside the new_mem output slot (204.8 MB),
  //      all uses finish before mem_update overwrites it ----
  char* orb = (char*)out_mem;
  bf16* qkv16 = (bf16*)(orb + 0);            // 50,331,648 B
  bf16* xgT   = (bf16*)(orb + 67108864);     // 67,108,864 B  [t][b][4096]
  bf16* xpe16 = (bf16*)(orb + 134217728);    // 16,777,216 B
  bf16* o16   = (bf16*)(orb + 150994944);    // 16,777,216 B
  bf16* ao16  = (bf16*)(orb + 167772160);    // 16,777,216 B
  bf16* raw16 = (bf16*)(orb + 184549376);    // 16,777,216 B (ends 201,326,592)
  float* embf = (float*)(orb + 201326592);   //  2,621,440 B (ends 203,948,032)

  // 1) weight conversions + bias sums
  f2b_kernel<<<3072, 256, 0, stream>>>(qkv_w, wq16, 786432);
  f2b_kernel<<<1024, 256, 0, stream>>>(out_w, wo16, 262144);
  f2b_kernel<<<4096, 256, 0, stream>>>(Wih0, wih0b, 1048576);
  f2b_kernel<<<4096, 256, 0, stream>>>(Whh0, whh0b, 1048576);
  f2b_kernel<<<4096, 256, 0, stream>>>(Wih1, wih1b, 1048576);
  f2b_kernel<<<4096, 256, 0, stream>>>(Whh1, whh1b, 1048576);
  add2_kernel<<<16, 256, 0, stream>>>(bih0, bhh0, bsum0, 4096);
  add2_kernel<<<16, 256, 0, stream>>>(bih1, bhh1, bsum1, 4096);

  // 2) encoder: 640-row emb table, then fused add -> xpe16
  emb_kernel<<<Tv * NS, 128, 0, stream>>>(enc_w1, enc_b1, enc_g1, enc_bb1,
                                          enc_w2, enc_b2, enc_g2, enc_bb2, embf);
  addemb_kernel<<<NT, 256, 0, stream>>>(x, stage, embf, xpe16);

  // 3) qkv = xpe @ qkv_w^T + b
  gemm128<<<dim3(NT / 128, 3072 / 128), 256, 0, stream>>>(xpe16, wq16, qkv_b, qkv16,
                                                          NT, 3072, Dv, 0);

  // 4) attention -> o16
  attn_kernel<<<Bv * Hv, 256, 0, stream>>>(qkv16, o16);

  // 5) out projection -> ao16
  gemm128<<<dim3(NT / 128, 1024 / 128), 256, 0, stream>>>(o16, wo16, out_b, ao16,
                                                          NT, Dv, Dv, 0);

  // 6) residual + LN -> raw (d_out) + raw16
  residual_ln_kernel<<<NT, 256, 0, stream>>>(xpe16, ao16, norm_g, norm_b, out_raw, raw16);

  // 7) layer-0 input gates (time-major), then fused 2-layer recurrence
  gemm128<<<dim3(NT / 128, 4096 / 128), 256, 0, stream>>>(raw16, wih0b, bsum0, xgT,
                                                          NT, 4096, Dv, 1);
  hipMemsetAsync(flags, 0, 1024, stream);
  lstm_fused<<<256, 256, 0, stream>>>(whh0b, wih1b, whh1b, xgT, bsum1,
                                      h0buf, h1buf, pooled, flags);

  // 8) raw_mean, gated fusion, head
  rawmean_kernel<<<256, 256, 0, stream>>>(out_raw, rawmean);
  gate1_kernel<<<Bv, 256, 0, stream>>>(pooled, rawmean, gate_w1, gate_b1, gt1);
  gate2_kernel<<<Bv, 256, 0, stream>>>(gt1, pooled, rawmean, gate_w2, gate_b2, out_fused);
  head_kernel<<<Bv, 128, 0, stream>>>(out_fused, head_w1, head_b1, head_g, head_bb,
                                      head_w2, head_b2, out_logits);

  // 9) memory bank update (overwrites the scratch region last)
  hipMemsetAsync(last, 0xFF, 5000 * 4, stream);
  scatter_last_kernel<<<32, 256, 0, stream>>>(cls, stage, last);
  mem_update_kernel<<<NC * NS, 256, 0, stream>>>(mem_in, out_raw, cnt_in, last, out_mem, out_cnt);
}